// Round 2
// baseline (4839.361 us; speedup 1.0000x reference)
//
#include <hip/hip_runtime.h>
#include <hip/hip_bf16.h>

#define B_   32
#define M_   512
#define E_   512
#define S_   513            // M+1
#define T_   (B_ * S_)      // 16416 tokens
#define NH_  8
#define DH_  64
#define F_   768
#define DFF_ 2048

// ---------------------------------------------------------------- PE table
__global__ void pe_kernel(float* __restrict__ pe) {
    int idx = blockIdx.x * blockDim.x + threadIdx.x;
    if (idx >= M_ * E_) return;
    int pos = idx / E_, i = idx % E_;
    double ex  = (double)((i >> 1) << 1) / (double)E_;
    double ang = (double)pos / pow(10000.0, ex);
    pe[idx] = (i & 1) ? (float)cos(ang) : (float)sin(ang);
}

// ---------------------------------------------------------------- span ids
// valid = prefix of spans with end != 0; span_id[b,k] = max valid j covering k, else -1
__global__ void span_kernel(const int* __restrict__ pos1, int* __restrict__ span) {
    int b = blockIdx.x;
    __shared__ int nv;
    if (threadIdx.x == 0) {
        int n = M_;
        for (int j = 0; j < M_; ++j) {
            if (pos1[(b * M_ + j) * 2 + 1] == 0) { n = j; break; }
        }
        nv = n;
    }
    __syncthreads();
    int n = nv;
    for (int k = threadIdx.x; k < M_; k += blockDim.x) {
        int best = -1;
        for (int j = 0; j < n; ++j) {
            int st = pos1[(b * M_ + j) * 2];
            int en = pos1[(b * M_ + j) * 2 + 1];
            if (st <= k && k < en) best = j;
        }
        span[b * M_ + k] = best;
    }
}

// ---------------------------------------------------------------- build x0 [B,S,E] f32
__global__ void build_x(const float* __restrict__ emb,
                        const int* __restrict__ pos2,
                        const float* __restrict__ fbase,
                        const float* __restrict__ pe,
                        const int* __restrict__ span,
                        float* __restrict__ x) {
    long long idx = (long long)blockIdx.x * blockDim.x + threadIdx.x;
    if (idx >= (long long)T_ * E_) return;
    int e = (int)(idx % E_);
    int t = (int)(idx / E_);
    int s = t % S_;
    int b = t / S_;
    float val;
    if (s == 0) {
        val = emb[E_ + e];                             // cls = emb_table[1]
    } else {
        int k = s - 1;
        int sid = span[b * M_ + k];
        if (sid >= 0) {
            int p = pos2[b * M_ + sid];
            val = emb[(size_t)p * E_ + e] + pe[sid * E_ + e];
        } else {
            val = fbase[((size_t)b * M_ + k) * E_ + e];
        }
    }
    x[idx] = val;
}

// ---------------------------------------------------------------- GEMM  C[t,o] = act(A[t,:]·W[o,:] + bias[o])
// A f32 [T,K] row-major, W f32 [O,K] row-major (torch Linear layout), K%16==0, O%64==0
template <int ACT>  // 0=none 1=relu 2=tanh
__global__ __launch_bounds__(256) void gemm_nt(const float* __restrict__ A,
                                               const float* __restrict__ W,
                                               const float* __restrict__ bias,
                                               float* __restrict__ C,
                                               int T, int K, int O) {
    __shared__ float sA[16][65];
    __shared__ float sB[16][65];
    int tid = threadIdx.x;
    int t0 = blockIdx.x * 64;
    int o0 = blockIdx.y * 64;
    int ty = tid >> 4, tx = tid & 15;
    float acc[4][4] = {{0.f}};
    int lin = tid * 4;
    int lt = lin >> 4;   // 0..63
    int lk = lin & 15;   // 0,4,8,12

    for (int k0 = 0; k0 < K; k0 += 16) {
        float4 av;
        int gt = t0 + lt;
        if (gt < T) av = *(const float4*)&A[(size_t)gt * K + k0 + lk];
        else        av = make_float4(0.f, 0.f, 0.f, 0.f);
        sA[lk + 0][lt] = av.x; sA[lk + 1][lt] = av.y;
        sA[lk + 2][lt] = av.z; sA[lk + 3][lt] = av.w;

        int go = o0 + lt;   // always < O (O % 64 == 0)
        float4 wv = *(const float4*)&W[(size_t)go * K + k0 + lk];
        sB[lk + 0][lt] = wv.x; sB[lk + 1][lt] = wv.y;
        sB[lk + 2][lt] = wv.z; sB[lk + 3][lt] = wv.w;
        __syncthreads();

#pragma unroll
        for (int k = 0; k < 16; ++k) {
            float a[4], bb[4];
#pragma unroll
            for (int i = 0; i < 4; ++i) a[i] = sA[k][ty * 4 + i];
#pragma unroll
            for (int j = 0; j < 4; ++j) bb[j] = sB[k][tx * 4 + j];
#pragma unroll
            for (int i = 0; i < 4; ++i)
#pragma unroll
                for (int j = 0; j < 4; ++j) acc[i][j] += a[i] * bb[j];
        }
        __syncthreads();
    }

#pragma unroll
    for (int i = 0; i < 4; ++i) {
        int gt = t0 + ty * 4 + i;
        if (gt >= T) continue;
#pragma unroll
        for (int j = 0; j < 4; ++j) {
            int go = o0 + tx * 4 + j;
            float v = acc[i][j];
            if (bias) v += bias[go];
            if (ACT == 1) v = fmaxf(v, 0.f);
            if (ACT == 2) v = tanhf(v);
            C[(size_t)gt * O + go] = v;
        }
    }
}

// ---------------------------------------------------------------- attention over the B axis
// qkv [T,1536] with t=b*S+s; block = (s,h); scores 32x32, softmax over keys m
__global__ __launch_bounds__(256) void attn_kernel(const float* __restrict__ qkv,
                                                   float* __restrict__ o) {
    __shared__ float q[32][65], kk[32][65], vv[32][65];
    __shared__ float sc[32][33];
    int s = blockIdx.x, h = blockIdx.y;
    int tid = threadIdx.x;

    for (int u = tid; u < B_ * DH_; u += 256) {
        int b = u >> 6, d = u & 63;
        size_t base = ((size_t)b * S_ + s) * 1536 + h * DH_ + d;
        q[b][d]  = qkv[base] * 0.125f;      // 1/sqrt(64)
        kk[b][d] = qkv[base + 512];
        vv[b][d] = qkv[base + 1024];
    }
    __syncthreads();

    for (int u = tid; u < 1024; u += 256) {
        int l = u >> 5, m = u & 31;
        float acc = 0.f;
#pragma unroll 8
        for (int d = 0; d < 64; ++d) acc += q[l][d] * kk[m][d];
        sc[l][m] = acc;
    }
    __syncthreads();

    if (tid < 32) {
        float mx = -1e30f;
        for (int m = 0; m < 32; ++m) mx = fmaxf(mx, sc[tid][m]);
        float sum = 0.f;
        for (int m = 0; m < 32; ++m) { float e = expf(sc[tid][m] - mx); sc[tid][m] = e; sum += e; }
        float inv = 1.f / sum;
        for (int m = 0; m < 32; ++m) sc[tid][m] *= inv;
    }
    __syncthreads();

    for (int u = tid; u < B_ * DH_; u += 256) {
        int l = u >> 6, d = u & 63;
        float acc = 0.f;
#pragma unroll 8
        for (int m = 0; m < 32; ++m) acc += sc[l][m] * vv[m][d];
        o[((size_t)l * S_ + s) * E_ + h * DH_ + d] = acc;
    }
}

// ---------------------------------------------------------------- x = LN(x + h) over E, per token
__global__ __launch_bounds__(256) void add_ln(float* __restrict__ x,
                                              const float* __restrict__ h,
                                              const float* __restrict__ w,
                                              const float* __restrict__ b) {
    int t = blockIdx.x;
    float* xr = x + (size_t)t * E_;
    const float* hr = h + (size_t)t * E_;
    int i0 = threadIdx.x * 2;
    float2 xv = *(const float2*)&xr[i0];
    float2 hv = *(const float2*)&hr[i0];
    float v0 = xv.x + hv.x, v1 = xv.y + hv.y;

    __shared__ float red[4];
    float sum = v0 + v1;
    for (int off = 32; off; off >>= 1) sum += __shfl_down(sum, off);
    if ((threadIdx.x & 63) == 0) red[threadIdx.x >> 6] = sum;
    __syncthreads();
    float mu = (red[0] + red[1] + red[2] + red[3]) * (1.0f / E_);
    __syncthreads();

    float d0 = v0 - mu, d1 = v1 - mu;
    float qs = d0 * d0 + d1 * d1;
    for (int off = 32; off; off >>= 1) qs += __shfl_down(qs, off);
    if ((threadIdx.x & 63) == 0) red[threadIdx.x >> 6] = qs;
    __syncthreads();
    float var = (red[0] + red[1] + red[2] + red[3]) * (1.0f / E_);
    float rstd = rsqrtf(var + 1e-5f);

    float o0 = d0 * rstd * w[i0]     + b[i0];
    float o1 = d1 * rstd * w[i0 + 1] + b[i0 + 1];
    *(float2*)&xr[i0] = make_float2(o0, o1);
}

// ---------------------------------------------------------------- discriminator + sigmoid
__global__ __launch_bounds__(256) void disc_kernel(const float* __restrict__ bert,
                                                   const float* __restrict__ pf,
                                                   const float* __restrict__ wd,
                                                   const float* __restrict__ bd,
                                                   float* __restrict__ out) {
    int t = blockIdx.x;
    float s = 0.f;
    for (int f = threadIdx.x; f < F_; f += 256) {
        s += bert[(size_t)t * F_ + f] * wd[f];
        s += pf[(size_t)t * F_ + f] * wd[F_ + f];
    }
    for (int off = 32; off; off >>= 1) s += __shfl_down(s, off);
    __shared__ float red[4];
    if ((threadIdx.x & 63) == 0) red[threadIdx.x >> 6] = s;
    __syncthreads();
    if (threadIdx.x == 0) {
        float z = red[0] + red[1] + red[2] + red[3] + bd[0];
        out[t] = 1.f / (1.f + expf(-z));
    }
}

// ---------------------------------------------------------------- launch
extern "C" void kernel_launch(void* const* d_in, const int* in_sizes, int n_in,
                              void* d_out, int out_size, void* d_ws, size_t ws_size,
                              hipStream_t stream) {
    const int*   pos1 = (const int*)d_in[0];
    const int*   pos2 = (const int*)d_in[1];
    const float* bert = (const float*)d_in[2];
    const float* fb   = (const float*)d_in[3];
    const float* emb  = (const float*)d_in[4];
    const float* wi   = (const float*)d_in[5];
    const float* bi   = (const float*)d_in[6];
    const float* wo   = (const float*)d_in[7];
    const float* bo   = (const float*)d_in[8];
    const float* ln1w = (const float*)d_in[9];
    const float* ln1b = (const float*)d_in[10];
    const float* ln2w = (const float*)d_in[11];
    const float* ln2b = (const float*)d_in[12];
    const float* w1   = (const float*)d_in[13];
    const float* b1   = (const float*)d_in[14];
    const float* w2   = (const float*)d_in[15];
    const float* b2   = (const float*)d_in[16];
    const float* wm   = (const float*)d_in[17];
    const float* wd   = (const float*)d_in[18];
    const float* bd   = (const float*)d_in[19];
    float* out = (float*)d_out;

    float* ws   = (float*)d_ws;
    float* pe   = ws;                                   // 262144 f
    int*   span = (int*)(ws + 262144);                  // 16384 i
    float* x    = ws + 262144 + 16384;                  // T*E f
    float* bufA = x + (size_t)T_ * E_;                  // T*DFF f (qkv/h1/pf reuse)
    float* bufB = bufA + (size_t)T_ * DFF_;             // T*E f

    pe_kernel<<<(M_ * E_ + 255) / 256, 256, 0, stream>>>(pe);
    span_kernel<<<B_, 256, 0, stream>>>(pos1, span);
    build_x<<<(int)(((long long)T_ * E_ + 255) / 256), 256, 0, stream>>>(emb, pos2, fb, pe, span, x);

    int gt = (T_ + 63) / 64;  // 257
    for (int l = 0; l < 2; ++l) {
        gemm_nt<0><<<dim3(gt, 1536 / 64), 256, 0, stream>>>(
            x, wi + (size_t)l * 1536 * E_, bi + l * 1536, bufA, T_, E_, 1536);
        attn_kernel<<<dim3(S_, NH_), 256, 0, stream>>>(bufA, bufB);
        gemm_nt<0><<<dim3(gt, E_ / 64), 256, 0, stream>>>(
            bufB, wo + (size_t)l * E_ * E_, bo + l * E_, bufA, T_, E_, E_);
        add_ln<<<T_, 256, 0, stream>>>(x, bufA, ln1w + l * E_, ln1b + l * E_);
        gemm_nt<1><<<dim3(gt, DFF_ / 64), 256, 0, stream>>>(
            x, w1 + (size_t)l * DFF_ * E_, b1 + l * DFF_, bufA, T_, E_, DFF_);
        gemm_nt<0><<<dim3(gt, E_ / 64), 256, 0, stream>>>(
            bufA, w2 + (size_t)l * E_ * DFF_, b2 + l * E_, bufB, T_, DFF_, E_);
        add_ln<<<T_, 256, 0, stream>>>(x, bufB, ln2w + l * E_, ln2b + l * E_);
    }
    gemm_nt<2><<<dim3(gt, F_ / 64), 256, 0, stream>>>(x, wm, nullptr, bufA, T_, E_, F_);
    disc_kernel<<<T_, 256, 0, stream>>>(bert, bufA, wd, bd, out);
}

// Round 4
// 1058.543 us; speedup vs baseline: 4.5717x; 4.5717x over previous
//
#include <hip/hip_runtime.h>
#include <hip/hip_bf16.h>

#define B_   32
#define M_   512
#define E_   512
#define S_   513            // M+1
#define T_   (B_ * S_)      // 16416 tokens
#define TP_  16512          // 129*128 padded
#define NH_  8
#define DH_  64
#define F_   768
#define DFF_ 2048

#define LDA_ 40             // LDS row stride in shorts (80B, 16B-aligned, conflict-light)

typedef short short8 __attribute__((ext_vector_type(8)));
typedef float floatx4 __attribute__((ext_vector_type(4)));

__device__ __forceinline__ float bf2f(unsigned short u) {
    return __uint_as_float(((unsigned int)u) << 16);
}
__device__ __forceinline__ unsigned short f2b_rne(float f) {
    unsigned int u = __float_as_uint(f);
    unsigned int r = u + 0x7FFF + ((u >> 16) & 1);
    return (unsigned short)(r >> 16);
}

// ---------------------------------------------------------------- PE table
__global__ void pe_kernel(float* __restrict__ pe) {
    int idx = blockIdx.x * blockDim.x + threadIdx.x;
    if (idx >= M_ * E_) return;
    int pos = idx / E_, i = idx % E_;
    double ex  = (double)((i >> 1) << 1) / (double)E_;
    double ang = (double)pos / pow(10000.0, ex);
    pe[idx] = (i & 1) ? (float)cos(ang) : (float)sin(ang);
}

// ---------------------------------------------------------------- span ids
__global__ void span_kernel(const int* __restrict__ pos1, int* __restrict__ span) {
    int b = blockIdx.x;
    __shared__ int nv;
    if (threadIdx.x == 0) {
        int n = M_;
        for (int j = 0; j < M_; ++j)
            if (pos1[(b * M_ + j) * 2 + 1] == 0) { n = j; break; }
        nv = n;
    }
    __syncthreads();
    int n = nv;
    for (int k = threadIdx.x; k < M_; k += blockDim.x) {
        int best = -1;
        for (int j = 0; j < n; ++j) {
            int st = pos1[(b * M_ + j) * 2];
            int en = pos1[(b * M_ + j) * 2 + 1];
            if (st <= k && k < en) best = j;
        }
        span[b * M_ + k] = best;
    }
}

// ---------------------------------------------------------------- f32 -> bf16
__global__ void f2b_kernel(const float* __restrict__ src, unsigned short* __restrict__ dst, int n) {
    int i = blockIdx.x * 256 + threadIdx.x;
    if (i < n) dst[i] = f2b_rne(src[i]);
}

// ---------------------------------------------------------------- build x0 (f32 + bf16 shadow)
__global__ void build_x(const float* __restrict__ emb,
                        const int* __restrict__ pos2,
                        const float* __restrict__ fbase,
                        const float* __restrict__ pe,
                        const int* __restrict__ span,
                        float* __restrict__ x,
                        unsigned short* __restrict__ xb) {
    long long idx = (long long)blockIdx.x * blockDim.x + threadIdx.x;
    if (idx >= (long long)T_ * E_) return;
    int e = (int)(idx % E_);
    int t = (int)(idx / E_);
    int s = t % S_;
    int b = t / S_;
    float val;
    if (s == 0) {
        val = emb[E_ + e];
    } else {
        int k = s - 1;
        int sid = span[b * M_ + k];
        if (sid >= 0) {
            int p = pos2[b * M_ + sid];
            val = emb[(size_t)p * E_ + e] + pe[sid * E_ + e];
        } else {
            val = fbase[((size_t)b * M_ + k) * E_ + e];
        }
    }
    x[idx] = val;
    xb[idx] = f2b_rne(val);
}

// ---------------------------------------------------------------- bf16 MFMA GEMM (NT)
// A [TP_,K] bf16 row-major, W [O,K] bf16 row-major; C[t,o] = act(A·W^T + bias)
// 128x128 tile, BK=32, 256 thr = 4 waves, each wave 64x64 via 4x4 mfma 16x16x32.
// Staging: explicit global short8 load -> ds_write_b128 (no global_load_lds).
template <int ACT, int BF16OUT>  // ACT: 0 none 1 relu 2 tanh
__global__ __launch_bounds__(256) void gemm_bf16(const unsigned short* __restrict__ A,
                                                 const unsigned short* __restrict__ W,
                                                 const float* __restrict__ bias,
                                                 float* __restrict__ Cf,
                                                 unsigned short* __restrict__ Cb,
                                                 int T, int K, int O) {
    __shared__ __align__(16) unsigned short sA[128 * LDA_];
    __shared__ __align__(16) unsigned short sB[128 * LDA_];
    int tid = threadIdx.x;
    int lane = tid & 63, wv = tid >> 6;
    int wr = (wv >> 1) * 64, wc = (wv & 1) * 64;
    int t0 = blockIdx.x * 128, o0 = blockIdx.y * 128;

    floatx4 acc[4][4] = {};

    // staging map: thread u covers (row = u>>2, chunk = u&3) and (+64 rows)
    int srow = tid >> 2;           // 0..63
    int schunk = (tid & 3) * 8;    // 0,8,16,24
    const unsigned short* Ag0 = A + (size_t)(t0 + srow) * K + schunk;
    const unsigned short* Ag1 = A + (size_t)(t0 + 64 + srow) * K + schunk;
    const unsigned short* Bg0 = W + (size_t)(o0 + srow) * K + schunk;
    const unsigned short* Bg1 = W + (size_t)(o0 + 64 + srow) * K + schunk;
    unsigned short* sA0 = sA + srow * LDA_ + schunk;
    unsigned short* sA1 = sA + (64 + srow) * LDA_ + schunk;
    unsigned short* sB0 = sB + srow * LDA_ + schunk;
    unsigned short* sB1 = sB + (64 + srow) * LDA_ + schunk;

    int fr = lane & 15;           // fragment row/col within 16
    int fk = (lane >> 4) * 8;     // fragment k offset

    for (int k0 = 0; k0 < K; k0 += 32) {
        short8 a0 = *(const short8*)(Ag0 + k0);
        short8 a1 = *(const short8*)(Ag1 + k0);
        short8 b0 = *(const short8*)(Bg0 + k0);
        short8 b1 = *(const short8*)(Bg1 + k0);
        *(short8*)sA0 = a0;
        *(short8*)sA1 = a1;
        *(short8*)sB0 = b0;
        *(short8*)sB1 = b1;
        __syncthreads();

        short8 af[4], bfr[4];
#pragma unroll
        for (int i = 0; i < 4; ++i)
            af[i] = *(const short8*)&sA[(wr + i * 16 + fr) * LDA_ + fk];
#pragma unroll
        for (int j = 0; j < 4; ++j)
            bfr[j] = *(const short8*)&sB[(wc + j * 16 + fr) * LDA_ + fk];
#pragma unroll
        for (int i = 0; i < 4; ++i)
#pragma unroll
            for (int j = 0; j < 4; ++j)
                acc[i][j] = __builtin_amdgcn_mfma_f32_16x16x32_bf16(af[i], bfr[j], acc[i][j], 0, 0, 0);
        __syncthreads();
    }

    int cr = (lane >> 4) * 4;     // C row base within 16
    int cc = lane & 15;           // C col within 16
#pragma unroll
    for (int i = 0; i < 4; ++i) {
#pragma unroll
        for (int j = 0; j < 4; ++j) {
            int gn = o0 + wc + j * 16 + cc;
            float bv = bias ? bias[gn] : 0.f;
#pragma unroll
            for (int r = 0; r < 4; ++r) {
                int gm = t0 + wr + i * 16 + cr + r;
                if (gm >= T) continue;
                float v = acc[i][j][r] + bv;
                if (ACT == 1) v = fmaxf(v, 0.f);
                if (ACT == 2) v = tanhf(v);
                if (BF16OUT) Cb[(size_t)gm * O + gn] = f2b_rne(v);
                else         Cf[(size_t)gm * O + gn] = v;
            }
        }
    }
}

// ---------------------------------------------------------------- attention over the B axis (bf16 in/out)
__global__ __launch_bounds__(256) void attn_kernel(const unsigned short* __restrict__ qkv,
                                                   unsigned short* __restrict__ o) {
    __shared__ float q[32][65], kk[32][65], vv[32][65];
    __shared__ float sc[32][33];
    int s = blockIdx.x, h = blockIdx.y;
    int tid = threadIdx.x;

    for (int u = tid; u < B_ * DH_; u += 256) {
        int b = u >> 6, d = u & 63;
        size_t base = ((size_t)b * S_ + s) * 1536 + h * DH_ + d;
        q[b][d]  = bf2f(qkv[base]) * 0.125f;
        kk[b][d] = bf2f(qkv[base + 512]);
        vv[b][d] = bf2f(qkv[base + 1024]);
    }
    __syncthreads();

    for (int u = tid; u < 1024; u += 256) {
        int l = u >> 5, m = u & 31;
        float acc = 0.f;
#pragma unroll 8
        for (int d = 0; d < 64; ++d) acc += q[l][d] * kk[m][d];
        sc[l][m] = acc;
    }
    __syncthreads();

    if (tid < 32) {
        float mx = -1e30f;
        for (int m = 0; m < 32; ++m) mx = fmaxf(mx, sc[tid][m]);
        float sum = 0.f;
        for (int m = 0; m < 32; ++m) { float e = expf(sc[tid][m] - mx); sc[tid][m] = e; sum += e; }
        float inv = 1.f / sum;
        for (int m = 0; m < 32; ++m) sc[tid][m] *= inv;
    }
    __syncthreads();

    for (int u = tid; u < B_ * DH_; u += 256) {
        int l = u >> 6, d = u & 63;
        float acc = 0.f;
#pragma unroll 8
        for (int m = 0; m < 32; ++m) acc += sc[l][m] * vv[m][d];
        o[((size_t)l * S_ + s) * E_ + h * DH_ + d] = f2b_rne(acc);
    }
}

// ---------------------------------------------------------------- x = LN(x + h); writes f32 + bf16 shadow
__global__ __launch_bounds__(256) void add_ln(float* __restrict__ x,
                                              unsigned short* __restrict__ xb,
                                              const float* __restrict__ h,
                                              const float* __restrict__ w,
                                              const float* __restrict__ b) {
    int t = blockIdx.x;
    float* xr = x + (size_t)t * E_;
    const float* hr = h + (size_t)t * E_;
    int i0 = threadIdx.x * 2;
    float2 xv = *(const float2*)&xr[i0];
    float2 hv = *(const float2*)&hr[i0];
    float v0 = xv.x + hv.x, v1 = xv.y + hv.y;

    __shared__ float red[4];
    float sum = v0 + v1;
    for (int off = 32; off; off >>= 1) sum += __shfl_down(sum, off);
    if ((threadIdx.x & 63) == 0) red[threadIdx.x >> 6] = sum;
    __syncthreads();
    float mu = (red[0] + red[1] + red[2] + red[3]) * (1.0f / E_);
    __syncthreads();

    float d0 = v0 - mu, d1 = v1 - mu;
    float qs = d0 * d0 + d1 * d1;
    for (int off = 32; off; off >>= 1) qs += __shfl_down(qs, off);
    if ((threadIdx.x & 63) == 0) red[threadIdx.x >> 6] = qs;
    __syncthreads();
    float var = (red[0] + red[1] + red[2] + red[3]) * (1.0f / E_);
    float rstd = rsqrtf(var + 1e-5f);

    float o0 = d0 * rstd * w[i0]     + b[i0];
    float o1 = d1 * rstd * w[i0 + 1] + b[i0 + 1];
    *(float2*)&xr[i0] = make_float2(o0, o1);
    xb[(size_t)t * E_ + i0]     = f2b_rne(o0);
    xb[(size_t)t * E_ + i0 + 1] = f2b_rne(o1);
}

// ---------------------------------------------------------------- discriminator + sigmoid
__global__ __launch_bounds__(256) void disc_kernel(const float* __restrict__ bert,
                                                   const float* __restrict__ pf,
                                                   const float* __restrict__ wd,
                                                   const float* __restrict__ bd,
                                                   float* __restrict__ out) {
    int t = blockIdx.x;
    float s = 0.f;
    for (int f = threadIdx.x; f < F_; f += 256) {
        s += bert[(size_t)t * F_ + f] * wd[f];
        s += pf[(size_t)t * F_ + f] * wd[F_ + f];
    }
    for (int off = 32; off; off >>= 1) s += __shfl_down(s, off);
    __shared__ float red[4];
    if ((threadIdx.x & 63) == 0) red[threadIdx.x >> 6] = s;
    __syncthreads();
    if (threadIdx.x == 0) {
        float z = red[0] + red[1] + red[2] + red[3] + bd[0];
        out[t] = 1.f / (1.f + expf(-z));
    }
}

// ---------------------------------------------------------------- launch
extern "C" void kernel_launch(void* const* d_in, const int* in_sizes, int n_in,
                              void* d_out, int out_size, void* d_ws, size_t ws_size,
                              hipStream_t stream) {
    const int*   pos1 = (const int*)d_in[0];
    const int*   pos2 = (const int*)d_in[1];
    const float* bert = (const float*)d_in[2];
    const float* fb   = (const float*)d_in[3];
    const float* emb  = (const float*)d_in[4];
    const float* wi   = (const float*)d_in[5];
    const float* bi   = (const float*)d_in[6];
    const float* wo   = (const float*)d_in[7];
    const float* bo   = (const float*)d_in[8];
    const float* ln1w = (const float*)d_in[9];
    const float* ln1b = (const float*)d_in[10];
    const float* ln2w = (const float*)d_in[11];
    const float* ln2b = (const float*)d_in[12];
    const float* w1   = (const float*)d_in[13];
    const float* b1   = (const float*)d_in[14];
    const float* w2   = (const float*)d_in[15];
    const float* b2   = (const float*)d_in[16];
    const float* wm   = (const float*)d_in[17];
    const float* wd   = (const float*)d_in[18];
    const float* bd   = (const float*)d_in[19];
    float* out = (float*)d_out;

    // workspace layout (float units); total ~183 MB
    float* ws   = (float*)d_ws;
    float* pe   = ws;                                         // 262144 f
    int*   span = (int*)(ws + 262144);                        // 16384 i
    float* x    = ws + 262144 + 16384;                        // T_*512 f
    float* hbuf = x + (size_t)T_ * 512;                       // T_*512 f
    unsigned short* xb   = (unsigned short*)(hbuf + (size_t)T_ * 512);   // TP_*512 bf16
    unsigned short* atb  = xb + (size_t)TP_ * 512;                       // TP_*512 bf16
    unsigned short* U    = atb + (size_t)TP_ * 512;                      // union: qkv_bf | h1_bf | pf
    unsigned short* qkvb = U;
    unsigned short* h1b  = U;
    float*          pf   = (float*)U;
    unsigned short* wib  = U + (size_t)TP_ * 2048;            // weights bf16
    unsigned short* wob  = wib + 2 * 1536 * 512;
    unsigned short* w1b  = wob + 2 * 512 * 512;
    unsigned short* w2b  = w1b + 2 * 2048 * 512;
    unsigned short* wmb  = w2b + 2 * 512 * 2048;

    pe_kernel<<<(M_ * E_ + 255) / 256, 256, 0, stream>>>(pe);
    span_kernel<<<B_, 256, 0, stream>>>(pos1, span);
    f2b_kernel<<<(2 * 1536 * 512 + 255) / 256, 256, 0, stream>>>(wi, wib, 2 * 1536 * 512);
    f2b_kernel<<<(2 * 512 * 512 + 255) / 256, 256, 0, stream>>>(wo, wob, 2 * 512 * 512);
    f2b_kernel<<<(2 * 2048 * 512 + 255) / 256, 256, 0, stream>>>(w1, w1b, 2 * 2048 * 512);
    f2b_kernel<<<(2 * 512 * 2048 + 255) / 256, 256, 0, stream>>>(w2, w2b, 2 * 512 * 2048);
    f2b_kernel<<<(768 * 512 + 255) / 256, 256, 0, stream>>>(wm, wmb, 768 * 512);
    build_x<<<(int)(((long long)T_ * 512 + 255) / 256), 256, 0, stream>>>(emb, pos2, fb, pe, span, x, xb);

    int gm = TP_ / 128;  // 129
    for (int l = 0; l < 2; ++l) {
        gemm_bf16<0, 1><<<dim3(gm, 1536 / 128), 256, 0, stream>>>(
            xb, wib + (size_t)l * 1536 * 512, bi + l * 1536, nullptr, qkvb, T_, 512, 1536);
        attn_kernel<<<dim3(S_, NH_), 256, 0, stream>>>(qkvb, atb);
        gemm_bf16<0, 0><<<dim3(gm, 512 / 128), 256, 0, stream>>>(
            atb, wob + (size_t)l * 512 * 512, bo + l * 512, hbuf, nullptr, T_, 512, 512);
        add_ln<<<T_, 256, 0, stream>>>(x, xb, hbuf, ln1w + l * 512, ln1b + l * 512);
        gemm_bf16<1, 1><<<dim3(gm, 2048 / 128), 256, 0, stream>>>(
            xb, w1b + (size_t)l * 2048 * 512, b1 + l * 2048, nullptr, h1b, T_, 512, 2048);
        gemm_bf16<0, 0><<<dim3(gm, 512 / 128), 256, 0, stream>>>(
            h1b, w2b + (size_t)l * 512 * 2048, b2 + l * 512, hbuf, nullptr, T_, 2048, 512);
        add_ln<<<T_, 256, 0, stream>>>(x, xb, hbuf, ln2w + l * 512, ln2b + l * 512);
    }
    gemm_bf16<2, 0><<<dim3(gm, 768 / 128), 256, 0, stream>>>(
        xb, wmb, nullptr, pf, nullptr, T_, 512, 768);
    disc_kernel<<<T_, 256, 0, stream>>>(bert, pf, wd, bd, out);
}

// Round 5
// 1026.797 us; speedup vs baseline: 4.7131x; 1.0309x over previous
//
#include <hip/hip_runtime.h>
#include <hip/hip_bf16.h>

#define B_   32
#define M_   512
#define E_   512
#define S_   513            // M+1
#define T_   (B_ * S_)      // 16416 tokens
#define TP_  16512          // 129*128 padded
#define NH_  8
#define DH_  64
#define F_   768
#define DFF_ 2048

#define LDA_ 40             // LDS row stride in shorts (80B, 16B-aligned)
#define GMT_ 129            // m tiles

typedef short short8 __attribute__((ext_vector_type(8)));
typedef float floatx4 __attribute__((ext_vector_type(4)));

__device__ __forceinline__ float bf2f(unsigned short u) {
    return __uint_as_float(((unsigned int)u) << 16);
}
__device__ __forceinline__ unsigned short f2b_rne(float f) {
    unsigned int u = __float_as_uint(f);
    unsigned int r = u + 0x7FFF + ((u >> 16) & 1);
    return (unsigned short)(r >> 16);
}

// ---------------------------------------------------------------- span ids
__global__ void span_kernel(const int* __restrict__ pos1, int* __restrict__ span) {
    int b = blockIdx.x;
    __shared__ int st[M_], en[M_];
    __shared__ int nv;
    int tid = threadIdx.x;
    for (int j = tid; j < M_; j += 256) {
        st[j] = pos1[(b * M_ + j) * 2];
        en[j] = pos1[(b * M_ + j) * 2 + 1];
    }
    __syncthreads();
    if (tid == 0) {
        int n = M_;
        for (int j = 0; j < M_; ++j) if (en[j] == 0) { n = j; break; }
        nv = n;
    }
    __syncthreads();
    int n = nv;
    for (int k = tid; k < M_; k += 256) {
        int best = -1;
        for (int j = 0; j < n; ++j)
            if (st[j] <= k && k < en[j]) best = j;
        span[b * M_ + k] = best;
    }
}

// ---------------------------------------------------------------- f32 -> bf16, 5 fused segments
__global__ void f2b5_kernel(const float* __restrict__ s0, const float* __restrict__ s1,
                            const float* __restrict__ s2, const float* __restrict__ s3,
                            const float* __restrict__ s4,
                            unsigned short* __restrict__ dst,
                            int c0, int c1, int c2, int c3, int c4) {
    int i = blockIdx.x * 256 + threadIdx.x;
    if (i >= c4) return;
    float v;
    if      (i < c0) v = s0[i];
    else if (i < c1) v = s1[i - c0];
    else if (i < c2) v = s2[i - c1];
    else if (i < c3) v = s3[i - c2];
    else             v = s4[i - c3];
    dst[i] = f2b_rne(v);
}

// ---------------------------------------------------------------- build x0 (f32 + bf16 shadow), PE inline
__global__ void build_x(const float* __restrict__ emb,
                        const int* __restrict__ pos2,
                        const float* __restrict__ fbase,
                        const int* __restrict__ span,
                        float* __restrict__ x,
                        unsigned short* __restrict__ xb) {
    long long idx = (long long)blockIdx.x * blockDim.x + threadIdx.x;
    if (idx >= (long long)T_ * E_) return;
    int e = (int)(idx % E_);
    int t = (int)(idx / E_);
    int s = t % S_;
    int b = t / S_;
    float val;
    if (s == 0) {
        val = emb[E_ + e];
    } else {
        int k = s - 1;
        int sid = span[b * M_ + k];
        if (sid >= 0) {
            int p = pos2[b * M_ + sid];
            // PE: ang = sid / 10000^(((e>>1)<<1)/512)
            float ex = (float)((e >> 1) << 1) * (1.0f / 512.0f);
            float ang = (float)sid * exp2f(-ex * 13.287712379549449f);  // log2(10000)
            float pe = (e & 1) ? cosf(ang) : sinf(ang);
            val = emb[(size_t)p * E_ + e] + pe;
        } else {
            val = fbase[((size_t)b * M_ + k) * E_ + e];
        }
    }
    x[idx] = val;
    xb[idx] = f2b_rne(val);
}

// ---------------------------------------------------------------- bf16 MFMA GEMM (NT)
// A [TP_,K] bf16, W [O,K] bf16; C = act(A·W^T + bias). Block 128xBN, 4 waves,
// wave tile 64x(BN/2), 4x(BN/32) grid of mfma 16x16x32, BK=32.
// 1-D grid with m-panel swizzle (8 m-tiles/panel, n fastest) for L2 locality.
template <int ACT, int BF16OUT, int BN>  // ACT: 0 none 1 relu 2 tanh
__global__ __launch_bounds__(256, 2) void gemm_bf16(const unsigned short* __restrict__ A,
                                                    const unsigned short* __restrict__ W,
                                                    const float* __restrict__ bias,
                                                    float* __restrict__ Cf,
                                                    unsigned short* __restrict__ Cb,
                                                    int T, int K, int O) {
    constexpr int NF = BN / 32;          // b-frags per wave
    __shared__ __align__(16) unsigned short sA[128 * LDA_];
    __shared__ __align__(16) unsigned short sB[BN * LDA_];
    int tid = threadIdx.x;
    int lane = tid & 63, wv = tid >> 6;
    int wr = (wv >> 1) * 64, wc = (wv & 1) * (BN / 2);

    // ---- panel swizzle
    int gn = O / BN;
    int per_panel = 8 * gn;
    int id = blockIdx.x;
    int p = id / per_panel;
    int r = id - p * per_panel;
    int mrem = GMT_ - p * 8; if (mrem > 8) mrem = 8;
    int mt = p * 8 + r % mrem;
    int nt = r / mrem;
    int t0 = mt * 128, o0 = nt * BN;

    floatx4 acc[4][NF] = {};

    // staging map: thread -> (row = tid>>2 [+64...], chunk = (tid&3)*8)
    int srow = tid >> 2;
    int schunk = (tid & 3) * 8;
    const unsigned short* Ag = A + (size_t)(t0 + srow) * K + schunk;
    const unsigned short* Bg = W + (size_t)(o0 + srow) * K + schunk;
    unsigned short* sAp = sA + srow * LDA_ + schunk;
    unsigned short* sBp = sB + srow * LDA_ + schunk;

    int fr = lane & 15;           // fragment row/col within 16
    int fk = (lane >> 4) * 8;     // fragment k offset

    for (int k0 = 0; k0 < K; k0 += 32) {
        short8 av0 = *(const short8*)(Ag + k0);
        short8 av1 = *(const short8*)(Ag + (size_t)64 * K + k0);
        short8 bv[BN / 64];
#pragma unroll
        for (int q = 0; q < BN / 64; ++q)
            bv[q] = *(const short8*)(Bg + (size_t)(64 * q) * K + k0);
        *(short8*)sAp = av0;
        *(short8*)(sAp + 64 * LDA_) = av1;
#pragma unroll
        for (int q = 0; q < BN / 64; ++q)
            *(short8*)(sBp + 64 * q * LDA_) = bv[q];
        __syncthreads();

        short8 af[4], bfr[NF];
#pragma unroll
        for (int i = 0; i < 4; ++i)
            af[i] = *(const short8*)&sA[(wr + i * 16 + fr) * LDA_ + fk];
#pragma unroll
        for (int j = 0; j < NF; ++j)
            bfr[j] = *(const short8*)&sB[(wc + j * 16 + fr) * LDA_ + fk];
#pragma unroll
        for (int i = 0; i < 4; ++i)
#pragma unroll
            for (int j = 0; j < NF; ++j)
                acc[i][j] = __builtin_amdgcn_mfma_f32_16x16x32_bf16(af[i], bfr[j], acc[i][j], 0, 0, 0);
        __syncthreads();
    }

    int cr = (lane >> 4) * 4;
    int cc = lane & 15;
#pragma unroll
    for (int i = 0; i < 4; ++i) {
#pragma unroll
        for (int j = 0; j < NF; ++j) {
            int gn_ = o0 + wc + j * 16 + cc;
            float bv = bias ? bias[gn_] : 0.f;
#pragma unroll
            for (int rr = 0; rr < 4; ++rr) {
                int gm_ = t0 + wr + i * 16 + cr + rr;
                if (gm_ >= T) continue;
                float v = acc[i][j][rr] + bv;
                if (ACT == 1) v = fmaxf(v, 0.f);
                if (ACT == 2) v = tanhf(v);
                if (BF16OUT) Cb[(size_t)gm_ * O + gn_] = f2b_rne(v);
                else         Cf[(size_t)gm_ * O + gn_] = v;
            }
        }
    }
}

// ---------------------------------------------------------------- attention over the B axis (bf16 in/out)
__global__ __launch_bounds__(256) void attn_kernel(const unsigned short* __restrict__ qkv,
                                                   unsigned short* __restrict__ o) {
    __shared__ float q[32][65], kk[32][65], vv[32][65];
    __shared__ float sc[32][33];
    int s = blockIdx.x, h = blockIdx.y;
    int tid = threadIdx.x;

    for (int u = tid; u < B_ * DH_; u += 256) {
        int b = u >> 6, d = u & 63;
        size_t base = ((size_t)b * S_ + s) * 1536 + h * DH_ + d;
        q[b][d]  = bf2f(qkv[base]) * 0.125f;
        kk[b][d] = bf2f(qkv[base + 512]);
        vv[b][d] = bf2f(qkv[base + 1024]);
    }
    __syncthreads();

    for (int u = tid; u < 1024; u += 256) {
        int l = u >> 5, m = u & 31;
        float acc = 0.f;
#pragma unroll 8
        for (int d = 0; d < 64; ++d) acc += q[l][d] * kk[m][d];
        sc[l][m] = acc;
    }
    __syncthreads();

    if (tid < 32) {
        float mx = -1e30f;
        for (int m = 0; m < 32; ++m) mx = fmaxf(mx, sc[tid][m]);
        float sum = 0.f;
        for (int m = 0; m < 32; ++m) { float e = expf(sc[tid][m] - mx); sc[tid][m] = e; sum += e; }
        float inv = 1.f / sum;
        for (int m = 0; m < 32; ++m) sc[tid][m] *= inv;
    }
    __syncthreads();

    for (int u = tid; u < B_ * DH_; u += 256) {
        int l = u >> 6, d = u & 63;
        float acc = 0.f;
#pragma unroll 8
        for (int m = 0; m < 32; ++m) acc += sc[l][m] * vv[m][d];
        o[((size_t)l * S_ + s) * E_ + h * DH_ + d] = f2b_rne(acc);
    }
}

// ---------------------------------------------------------------- x = LN(x + h); writes f32 + bf16 shadow
__global__ __launch_bounds__(256) void add_ln(float* __restrict__ x,
                                              unsigned short* __restrict__ xb,
                                              const float* __restrict__ h,
                                              const float* __restrict__ w,
                                              const float* __restrict__ b) {
    int t = blockIdx.x;
    float* xr = x + (size_t)t * E_;
    const float* hr = h + (size_t)t * E_;
    int i0 = threadIdx.x * 2;
    float2 xv = *(const float2*)&xr[i0];
    float2 hv = *(const float2*)&hr[i0];
    float v0 = xv.x + hv.x, v1 = xv.y + hv.y;

    __shared__ float red[4];
    float sum = v0 + v1;
    for (int off = 32; off; off >>= 1) sum += __shfl_down(sum, off);
    if ((threadIdx.x & 63) == 0) red[threadIdx.x >> 6] = sum;
    __syncthreads();
    float mu = (red[0] + red[1] + red[2] + red[3]) * (1.0f / E_);
    __syncthreads();

    float d0 = v0 - mu, d1 = v1 - mu;
    float qs = d0 * d0 + d1 * d1;
    for (int off = 32; off; off >>= 1) qs += __shfl_down(qs, off);
    if ((threadIdx.x & 63) == 0) red[threadIdx.x >> 6] = qs;
    __syncthreads();
    float var = (red[0] + red[1] + red[2] + red[3]) * (1.0f / E_);
    float rstd = rsqrtf(var + 1e-5f);

    float o0 = d0 * rstd * w[i0]     + b[i0];
    float o1 = d1 * rstd * w[i0 + 1] + b[i0 + 1];
    *(float2*)&xr[i0] = make_float2(o0, o1);
    xb[(size_t)t * E_ + i0]     = f2b_rne(o0);
    xb[(size_t)t * E_ + i0 + 1] = f2b_rne(o1);
}

// ---------------------------------------------------------------- discriminator + sigmoid (pf in bf16)
__global__ __launch_bounds__(256) void disc_kernel(const float* __restrict__ bert,
                                                   const unsigned short* __restrict__ pf,
                                                   const float* __restrict__ wd,
                                                   const float* __restrict__ bd,
                                                   float* __restrict__ out) {
    int t = blockIdx.x;
    float s = 0.f;
    for (int f = threadIdx.x; f < F_; f += 256) {
        s += bert[(size_t)t * F_ + f] * wd[f];
        s += bf2f(pf[(size_t)t * F_ + f]) * wd[F_ + f];
    }
    for (int off = 32; off; off >>= 1) s += __shfl_down(s, off);
    __shared__ float red[4];
    if ((threadIdx.x & 63) == 0) red[threadIdx.x >> 6] = s;
    __syncthreads();
    if (threadIdx.x == 0) {
        float z = red[0] + red[1] + red[2] + red[3] + bd[0];
        out[t] = 1.f / (1.f + expf(-z));
    }
}

// ---------------------------------------------------------------- launch
extern "C" void kernel_launch(void* const* d_in, const int* in_sizes, int n_in,
                              void* d_out, int out_size, void* d_ws, size_t ws_size,
                              hipStream_t stream) {
    const int*   pos1 = (const int*)d_in[0];
    const int*   pos2 = (const int*)d_in[1];
    const float* bert = (const float*)d_in[2];
    const float* fb   = (const float*)d_in[3];
    const float* emb  = (const float*)d_in[4];
    const float* wi   = (const float*)d_in[5];
    const float* bi   = (const float*)d_in[6];
    const float* wo   = (const float*)d_in[7];
    const float* bo   = (const float*)d_in[8];
    const float* ln1w = (const float*)d_in[9];
    const float* ln1b = (const float*)d_in[10];
    const float* ln2w = (const float*)d_in[11];
    const float* ln2b = (const float*)d_in[12];
    const float* w1   = (const float*)d_in[13];
    const float* b1   = (const float*)d_in[14];
    const float* w2   = (const float*)d_in[15];
    const float* b2   = (const float*)d_in[16];
    const float* wm   = (const float*)d_in[17];
    const float* wd   = (const float*)d_in[18];
    const float* bd   = (const float*)d_in[19];
    float* out = (float*)d_out;

    // workspace layout (float units)
    float* ws   = (float*)d_ws;
    int*   span = (int*)ws;                                   // 16384 i
    float* x    = ws + 16384;                                 // T_*512 f
    float* hbuf = x + (size_t)T_ * 512;                       // T_*512 f
    unsigned short* xb   = (unsigned short*)(hbuf + (size_t)T_ * 512);   // TP_*512 bf16
    unsigned short* atb  = xb + (size_t)TP_ * 512;                       // TP_*512 bf16
    unsigned short* U    = atb + (size_t)TP_ * 512;                      // union: qkv_bf | h1_bf | pf(bf16)
    unsigned short* qkvb = U;
    unsigned short* h1b  = U;
    unsigned short* pfb  = U;
    unsigned short* wib  = U + (size_t)TP_ * 2048;            // weights bf16, contiguous
    const int NWI = 2 * 1536 * 512;
    const int NWO = 2 * 512 * 512;
    const int NW1 = 2 * 2048 * 512;
    const int NW2 = 2 * 512 * 2048;
    const int NWM = 768 * 512;
    unsigned short* wob = wib + NWI;
    unsigned short* w1b = wob + NWO;
    unsigned short* w2b = w1b + NW1;
    unsigned short* wmb = w2b + NW2;

    span_kernel<<<B_, 256, 0, stream>>>(pos1, span);
    {
        int c0 = NWI, c1 = c0 + NWO, c2 = c1 + NW1, c3 = c2 + NW2, c4 = c3 + NWM;
        f2b5_kernel<<<(c4 + 255) / 256, 256, 0, stream>>>(wi, wo, w1, w2, wm, wib,
                                                          c0, c1, c2, c3, c4);
    }
    build_x<<<(int)(((long long)T_ * 512 + 255) / 256), 256, 0, stream>>>(emb, pos2, fb, span, x, xb);

    for (int l = 0; l < 2; ++l) {
        gemm_bf16<0, 1, 256><<<GMT_ * (1536 / 256), 256, 0, stream>>>(
            xb, wib + (size_t)l * 1536 * 512, bi + l * 1536, nullptr, qkvb, T_, 512, 1536);
        attn_kernel<<<dim3(S_, NH_), 256, 0, stream>>>(qkvb, atb);
        gemm_bf16<0, 0, 128><<<GMT_ * (512 / 128), 256, 0, stream>>>(
            atb, wob + (size_t)l * 512 * 512, bo + l * 512, hbuf, nullptr, T_, 512, 512);
        add_ln<<<T_, 256, 0, stream>>>(x, xb, hbuf, ln1w + l * 512, ln1b + l * 512);
        gemm_bf16<1, 1, 256><<<GMT_ * (2048 / 256), 256, 0, stream>>>(
            xb, w1b + (size_t)l * 2048 * 512, b1 + l * 2048, nullptr, h1b, T_, 512, 2048);
        gemm_bf16<0, 0, 128><<<GMT_ * (512 / 128), 256, 0, stream>>>(
            h1b, w2b + (size_t)l * 512 * 2048, b2 + l * 512, hbuf, nullptr, T_, 2048, 512);
        add_ln<<<T_, 256, 0, stream>>>(x, xb, hbuf, ln2w + l * 512, ln2b + l * 512);
    }
    gemm_bf16<2, 1, 256><<<GMT_ * (768 / 256), 256, 0, stream>>>(
        xb, wmb, nullptr, nullptr, pfb, T_, 512, 768);
    disc_kernel<<<T_, 256, 0, stream>>>(bert, pfb, wd, bd, out);
}

// Round 6
// 893.071 us; speedup vs baseline: 5.4188x; 1.1497x over previous
//
#include <hip/hip_runtime.h>
#include <hip/hip_bf16.h>

#define B_   32
#define M_   512
#define E_   512
#define S_   513            // M+1
#define T_   (B_ * S_)      // 16416 tokens
#define TP_  16512          // 129*128 padded
#define NH_  8
#define DH_  64
#define F_   768
#define DFF_ 2048

#define LDA_ 40             // LDS row stride in shorts (80B, 16B-aligned)
#define GMT_ 129            // m tiles

typedef short short8 __attribute__((ext_vector_type(8)));
typedef float floatx4 __attribute__((ext_vector_type(4)));

__device__ __forceinline__ float bf2f(unsigned short u) {
    return __uint_as_float(((unsigned int)u) << 16);
}
__device__ __forceinline__ unsigned short f2b_rne(float f) {
    unsigned int u = __float_as_uint(f);
    unsigned int r = u + 0x7FFF + ((u >> 16) & 1);
    return (unsigned short)(r >> 16);
}

// ---------------------------------------------------------------- span ids
__global__ void span_kernel(const int* __restrict__ pos1, int* __restrict__ span) {
    int b = blockIdx.x;
    __shared__ int st[M_], en[M_];
    __shared__ int nv;
    int tid = threadIdx.x;
    for (int j = tid; j < M_; j += 256) {
        st[j] = pos1[(b * M_ + j) * 2];
        en[j] = pos1[(b * M_ + j) * 2 + 1];
    }
    __syncthreads();
    if (tid == 0) {
        int n = M_;
        for (int j = 0; j < M_; ++j) if (en[j] == 0) { n = j; break; }
        nv = n;
    }
    __syncthreads();
    int n = nv;
    for (int k = tid; k < M_; k += 256) {
        int best = -1;
        for (int j = 0; j < n; ++j)
            if (st[j] <= k && k < en[j]) best = j;
        span[b * M_ + k] = best;
    }
}

// ---------------------------------------------------------------- f32 -> bf16, 5 fused segments
__global__ void f2b5_kernel(const float* __restrict__ s0, const float* __restrict__ s1,
                            const float* __restrict__ s2, const float* __restrict__ s3,
                            const float* __restrict__ s4,
                            unsigned short* __restrict__ dst,
                            int c0, int c1, int c2, int c3, int c4) {
    int i = blockIdx.x * 256 + threadIdx.x;
    if (i >= c4) return;
    float v;
    if      (i < c0) v = s0[i];
    else if (i < c1) v = s1[i - c0];
    else if (i < c2) v = s2[i - c1];
    else if (i < c3) v = s3[i - c2];
    else             v = s4[i - c3];
    dst[i] = f2b_rne(v);
}

// ---------------------------------------------------------------- build x0 (f32 + bf16 shadow), PE inline
__global__ void build_x(const float* __restrict__ emb,
                        const int* __restrict__ pos2,
                        const float* __restrict__ fbase,
                        const int* __restrict__ span,
                        float* __restrict__ x,
                        unsigned short* __restrict__ xb) {
    long long idx = (long long)blockIdx.x * blockDim.x + threadIdx.x;
    if (idx >= (long long)T_ * E_) return;
    int e = (int)(idx % E_);
    int t = (int)(idx / E_);
    int s = t % S_;
    int b = t / S_;
    float val;
    if (s == 0) {
        val = emb[E_ + e];
    } else {
        int k = s - 1;
        int sid = span[b * M_ + k];
        if (sid >= 0) {
            int p = pos2[b * M_ + sid];
            float ex = (float)((e >> 1) << 1) * (1.0f / 512.0f);
            float ang = (float)sid * exp2f(-ex * 13.287712379549449f);  // log2(10000)
            float pe = (e & 1) ? cosf(ang) : sinf(ang);
            val = emb[(size_t)p * E_ + e] + pe;
        } else {
            val = fbase[((size_t)b * M_ + k) * E_ + e];
        }
    }
    x[idx] = val;
    xb[idx] = f2b_rne(val);
}

// ---------------------------------------------------------------- bf16 MFMA GEMM (NT), pipelined
// A [TP_,K] bf16, W [O,K] bf16; C = act(A·W^T + bias), bf16 out.
// Block 128x128, 4 waves, wave tile 64x64 (4x4 mfma 16x16x32), BK=32.
// Double-buffered LDS + register prefetch: ONE barrier per K-step; the
// vmcnt wait for the prefetch lands after the MFMAs.
template <int ACT, int KT>  // ACT: 0 none 1 relu 2 tanh
__global__ __launch_bounds__(256, 3) void gemm_bf16(const unsigned short* __restrict__ A,
                                                    const unsigned short* __restrict__ W,
                                                    const float* __restrict__ bias,
                                                    unsigned short* __restrict__ Cb,
                                                    int T, int O) {
    constexpr int K = KT;
    __shared__ __align__(16) unsigned short sA[2][128 * LDA_];
    __shared__ __align__(16) unsigned short sB[2][128 * LDA_];
    int tid = threadIdx.x;
    int lane = tid & 63, wv = tid >> 6;
    int wr = (wv >> 1) * 64, wc = (wv & 1) * 64;

    // ---- panel swizzle: 8 m-tiles per panel, n fastest within panel
    int gn = O / 128;
    int per_panel = 8 * gn;
    int id = blockIdx.x;
    int p = id / per_panel;
    int r = id - p * per_panel;
    int mrem = GMT_ - p * 8; if (mrem > 8) mrem = 8;
    int mt = p * 8 + r % mrem;
    int nt = r / mrem;
    int t0 = mt * 128, o0 = nt * 128;

    floatx4 acc[4][4] = {};

    // staging map: thread -> rows (tid>>2, +64), chunk (tid&3)*8
    int srow = tid >> 2;
    int schunk = (tid & 3) * 8;
    const unsigned short* Ag = A + (size_t)(t0 + srow) * K + schunk;
    const unsigned short* Bg = W + (size_t)(o0 + srow) * K + schunk;
    int soff = srow * LDA_ + schunk;

    int fr = lane & 15;
    int fk = (lane >> 4) * 8;

    // prologue: tile 0 -> LDS[0]
    {
        short8 a0 = *(const short8*)(Ag);
        short8 a1 = *(const short8*)(Ag + (size_t)64 * K);
        short8 b0 = *(const short8*)(Bg);
        short8 b1 = *(const short8*)(Bg + (size_t)64 * K);
        *(short8*)&sA[0][soff] = a0;
        *(short8*)&sA[0][soff + 64 * LDA_] = a1;
        *(short8*)&sB[0][soff] = b0;
        *(short8*)&sB[0][soff + 64 * LDA_] = b1;
    }
    __syncthreads();

#pragma unroll
    for (int k0 = 0; k0 < K; k0 += 32) {
        const int cur = (k0 >> 5) & 1;
        const bool more = (k0 + 32 < K);
        short8 na0, na1, nb0, nb1;
        if (more) {
            na0 = *(const short8*)(Ag + k0 + 32);
            na1 = *(const short8*)(Ag + (size_t)64 * K + k0 + 32);
            nb0 = *(const short8*)(Bg + k0 + 32);
            nb1 = *(const short8*)(Bg + (size_t)64 * K + k0 + 32);
        }

        short8 af[4], bfr[4];
#pragma unroll
        for (int i = 0; i < 4; ++i)
            af[i] = *(const short8*)&sA[cur][(wr + i * 16 + fr) * LDA_ + fk];
#pragma unroll
        for (int j = 0; j < 4; ++j)
            bfr[j] = *(const short8*)&sB[cur][(wc + j * 16 + fr) * LDA_ + fk];
#pragma unroll
        for (int i = 0; i < 4; ++i)
#pragma unroll
            for (int j = 0; j < 4; ++j)
                acc[i][j] = __builtin_amdgcn_mfma_f32_16x16x32_bf16(af[i], bfr[j], acc[i][j], 0, 0, 0);

        if (more) {
            *(short8*)&sA[cur ^ 1][soff] = na0;
            *(short8*)&sA[cur ^ 1][soff + 64 * LDA_] = na1;
            *(short8*)&sB[cur ^ 1][soff] = nb0;
            *(short8*)&sB[cur ^ 1][soff + 64 * LDA_] = nb1;
        }
        __syncthreads();
    }

    int cr = (lane >> 4) * 4;
    int cc = lane & 15;
#pragma unroll
    for (int i = 0; i < 4; ++i) {
#pragma unroll
        for (int j = 0; j < 4; ++j) {
            int gn_ = o0 + wc + j * 16 + cc;
            float bv = bias ? bias[gn_] : 0.f;
#pragma unroll
            for (int rr = 0; rr < 4; ++rr) {
                int gm_ = t0 + wr + i * 16 + cr + rr;
                if (gm_ >= T) continue;
                float v = acc[i][j][rr] + bv;
                if (ACT == 1) v = fmaxf(v, 0.f);
                if (ACT == 2) v = tanhf(v);
                Cb[(size_t)gm_ * O + gn_] = f2b_rne(v);
            }
        }
    }
}

// ---------------------------------------------------------------- attention over the B axis (bf16 in/out)
__global__ __launch_bounds__(256) void attn_kernel(const unsigned short* __restrict__ qkv,
                                                   unsigned short* __restrict__ o) {
    __shared__ float q[32][65], kk[32][65], vv[32][65];
    __shared__ float sc[32][33];
    int s = blockIdx.x, h = blockIdx.y;
    int tid = threadIdx.x;

    for (int u = tid; u < B_ * DH_; u += 256) {
        int b = u >> 6, d = u & 63;
        size_t base = ((size_t)b * S_ + s) * 1536 + h * DH_ + d;
        q[b][d]  = bf2f(qkv[base]) * 0.125f;
        kk[b][d] = bf2f(qkv[base + 512]);
        vv[b][d] = bf2f(qkv[base + 1024]);
    }
    __syncthreads();

    for (int u = tid; u < 1024; u += 256) {
        int l = u >> 5, m = u & 31;
        float acc = 0.f;
#pragma unroll 8
        for (int d = 0; d < 64; ++d) acc += q[l][d] * kk[m][d];
        sc[l][m] = acc;
    }
    __syncthreads();

    if (tid < 32) {
        float mx = -1e30f;
        for (int m = 0; m < 32; ++m) mx = fmaxf(mx, sc[tid][m]);
        float sum = 0.f;
        for (int m = 0; m < 32; ++m) { float e = expf(sc[tid][m] - mx); sc[tid][m] = e; sum += e; }
        float inv = 1.f / sum;
        for (int m = 0; m < 32; ++m) sc[tid][m] *= inv;
    }
    __syncthreads();

    for (int u = tid; u < B_ * DH_; u += 256) {
        int l = u >> 6, d = u & 63;
        float acc = 0.f;
#pragma unroll 8
        for (int m = 0; m < 32; ++m) acc += sc[l][m] * vv[m][d];
        o[((size_t)l * S_ + s) * E_ + h * DH_ + d] = f2b_rne(acc);
    }
}

// ---------------------------------------------------------------- x = LN(x + h); h in bf16; writes f32 + bf16 shadow
__global__ __launch_bounds__(256) void add_ln(float* __restrict__ x,
                                              unsigned short* __restrict__ xb,
                                              const unsigned short* __restrict__ h,
                                              const float* __restrict__ w,
                                              const float* __restrict__ b) {
    int t = blockIdx.x;
    float* xr = x + (size_t)t * E_;
    const unsigned short* hr = h + (size_t)t * E_;
    int i0 = threadIdx.x * 2;
    float2 xv = *(const float2*)&xr[i0];
    ushort2 hv = *(const ushort2*)&hr[i0];
    float v0 = xv.x + bf2f(hv.x), v1 = xv.y + bf2f(hv.y);

    __shared__ float red[4];
    float sum = v0 + v1;
    for (int off = 32; off; off >>= 1) sum += __shfl_down(sum, off);
    if ((threadIdx.x & 63) == 0) red[threadIdx.x >> 6] = sum;
    __syncthreads();
    float mu = (red[0] + red[1] + red[2] + red[3]) * (1.0f / E_);
    __syncthreads();

    float d0 = v0 - mu, d1 = v1 - mu;
    float qs = d0 * d0 + d1 * d1;
    for (int off = 32; off; off >>= 1) qs += __shfl_down(qs, off);
    if ((threadIdx.x & 63) == 0) red[threadIdx.x >> 6] = qs;
    __syncthreads();
    float var = (red[0] + red[1] + red[2] + red[3]) * (1.0f / E_);
    float rstd = rsqrtf(var + 1e-5f);

    float o0 = d0 * rstd * w[i0]     + b[i0];
    float o1 = d1 * rstd * w[i0 + 1] + b[i0 + 1];
    *(float2*)&xr[i0] = make_float2(o0, o1);
    xb[(size_t)t * E_ + i0]     = f2b_rne(o0);
    xb[(size_t)t * E_ + i0 + 1] = f2b_rne(o1);
}

// ---------------------------------------------------------------- discriminator + sigmoid (pf in bf16)
__global__ __launch_bounds__(256) void disc_kernel(const float* __restrict__ bert,
                                                   const unsigned short* __restrict__ pf,
                                                   const float* __restrict__ wd,
                                                   const float* __restrict__ bd,
                                                   float* __restrict__ out) {
    int t = blockIdx.x;
    float s = 0.f;
    for (int f = threadIdx.x; f < F_; f += 256) {
        s += bert[(size_t)t * F_ + f] * wd[f];
        s += bf2f(pf[(size_t)t * F_ + f]) * wd[F_ + f];
    }
    for (int off = 32; off; off >>= 1) s += __shfl_down(s, off);
    __shared__ float red[4];
    if ((threadIdx.x & 63) == 0) red[threadIdx.x >> 6] = s;
    __syncthreads();
    if (threadIdx.x == 0) {
        float z = red[0] + red[1] + red[2] + red[3] + bd[0];
        out[t] = 1.f / (1.f + expf(-z));
    }
}

// ---------------------------------------------------------------- launch
extern "C" void kernel_launch(void* const* d_in, const int* in_sizes, int n_in,
                              void* d_out, int out_size, void* d_ws, size_t ws_size,
                              hipStream_t stream) {
    const int*   pos1 = (const int*)d_in[0];
    const int*   pos2 = (const int*)d_in[1];
    const float* bert = (const float*)d_in[2];
    const float* fb   = (const float*)d_in[3];
    const float* emb  = (const float*)d_in[4];
    const float* wi   = (const float*)d_in[5];
    const float* bi   = (const float*)d_in[6];
    const float* wo   = (const float*)d_in[7];
    const float* bo   = (const float*)d_in[8];
    const float* ln1w = (const float*)d_in[9];
    const float* ln1b = (const float*)d_in[10];
    const float* ln2w = (const float*)d_in[11];
    const float* ln2b = (const float*)d_in[12];
    const float* w1   = (const float*)d_in[13];
    const float* b1   = (const float*)d_in[14];
    const float* w2   = (const float*)d_in[15];
    const float* b2   = (const float*)d_in[16];
    const float* wm   = (const float*)d_in[17];
    const float* wd   = (const float*)d_in[18];
    const float* bd   = (const float*)d_in[19];
    float* out = (float*)d_out;

    // workspace layout
    float* ws   = (float*)d_ws;
    int*   span = (int*)ws;                                   // 16384 i
    float* x    = ws + 16384;                                 // T_*512 f
    unsigned short* xb  = (unsigned short*)(x + (size_t)T_ * 512);   // TP_*512 bf16
    unsigned short* atb = xb + (size_t)TP_ * 512;                    // TP_*512 bf16
    unsigned short* hb  = atb + (size_t)TP_ * 512;                   // T_*512 bf16
    unsigned short* U   = hb + (size_t)T_ * 512;              // union: qkv | h1 | pf
    unsigned short* qkvb = U;
    unsigned short* h1b  = U;
    unsigned short* pfb  = U;
    unsigned short* wib  = U + (size_t)TP_ * 2048;            // weights bf16, contiguous
    const int NWI = 2 * 1536 * 512;
    const int NWO = 2 * 512 * 512;
    const int NW1 = 2 * 2048 * 512;
    const int NW2 = 2 * 512 * 2048;
    const int NWM = 768 * 512;
    unsigned short* wob = wib + NWI;
    unsigned short* w1b = wob + NWO;
    unsigned short* w2b = w1b + NW1;
    unsigned short* wmb = w2b + NW2;

    span_kernel<<<B_, 256, 0, stream>>>(pos1, span);
    {
        int c0 = NWI, c1 = c0 + NWO, c2 = c1 + NW1, c3 = c2 + NW2, c4 = c3 + NWM;
        f2b5_kernel<<<(c4 + 255) / 256, 256, 0, stream>>>(wi, wo, w1, w2, wm, wib,
                                                          c0, c1, c2, c3, c4);
    }
    build_x<<<(int)(((long long)T_ * 512 + 255) / 256), 256, 0, stream>>>(emb, pos2, fb, span, x, xb);

    for (int l = 0; l < 2; ++l) {
        gemm_bf16<0, 512><<<GMT_ * (1536 / 128), 256, 0, stream>>>(
            xb, wib + (size_t)l * 1536 * 512, bi + l * 1536, qkvb, T_, 1536);
        attn_kernel<<<dim3(S_, NH_), 256, 0, stream>>>(qkvb, atb);
        gemm_bf16<0, 512><<<GMT_ * (512 / 128), 256, 0, stream>>>(
            atb, wob + (size_t)l * 512 * 512, bo + l * 512, hb, T_, 512);
        add_ln<<<T_, 256, 0, stream>>>(x, xb, hb, ln1w + l * 512, ln1b + l * 512);
        gemm_bf16<1, 512><<<GMT_ * (2048 / 128), 256, 0, stream>>>(
            xb, w1b + (size_t)l * 2048 * 512, b1 + l * 2048, h1b, T_, 2048);
        gemm_bf16<0, 2048><<<GMT_ * (512 / 128), 256, 0, stream>>>(
            h1b, w2b + (size_t)l * 512 * 2048, b2 + l * 512, hb, T_, 512);
        add_ln<<<T_, 256, 0, stream>>>(x, xb, hb, ln2w + l * 512, ln2b + l * 512);
    }
    gemm_bf16<2, 512><<<GMT_ * (768 / 128), 256, 0, stream>>>(
        xb, wmb, nullptr, pfb, T_, 768);
    disc_kernel<<<T_, 256, 0, stream>>>(bert, pfb, wd, bd, out);
}

// Round 7
// 885.374 us; speedup vs baseline: 5.4659x; 1.0087x over previous
//
#include <hip/hip_runtime.h>
#include <hip/hip_bf16.h>

#define B_   32
#define M_   512
#define E_   512
#define S_   513            // M+1
#define T_   (B_ * S_)      // 16416 tokens
#define TP_  16512          // 129*128 padded
#define NH_  8
#define DH_  64
#define F_   768
#define DFF_ 2048

#define GMT_ 129            // m tiles

typedef short short8 __attribute__((ext_vector_type(8)));
typedef float floatx4 __attribute__((ext_vector_type(4)));

__device__ __forceinline__ float bf2f(unsigned short u) {
    return __uint_as_float(((unsigned int)u) << 16);
}
__device__ __forceinline__ unsigned short f2b_rne(float f) {
    unsigned int u = __float_as_uint(f);
    unsigned int r = u + 0x7FFF + ((u >> 16) & 1);
    return (unsigned short)(r >> 16);
}
__device__ __forceinline__ void gload16(const void* g, void* l) {
    __builtin_amdgcn_global_load_lds(
        (const __attribute__((address_space(1))) void*)g,
        (__attribute__((address_space(3))) void*)l, 16, 0, 0);
}
// wait vmcnt(0) only (expcnt=7, lgkmcnt=15 -> no wait): gfx9 encoding 0x0F70
__device__ __forceinline__ void wait_vm0() { __builtin_amdgcn_s_waitcnt(0x0F70); }

// ---------------------------------------------------------------- span ids
__global__ void span_kernel(const int* __restrict__ pos1, int* __restrict__ span) {
    int b = blockIdx.x;
    __shared__ int st[M_], en[M_];
    __shared__ int nv;
    int tid = threadIdx.x;
    for (int j = tid; j < M_; j += 256) {
        st[j] = pos1[(b * M_ + j) * 2];
        en[j] = pos1[(b * M_ + j) * 2 + 1];
    }
    __syncthreads();
    if (tid == 0) {
        int n = M_;
        for (int j = 0; j < M_; ++j) if (en[j] == 0) { n = j; break; }
        nv = n;
    }
    __syncthreads();
    int n = nv;
    for (int k = tid; k < M_; k += 256) {
        int best = -1;
        for (int j = 0; j < n; ++j)
            if (st[j] <= k && k < en[j]) best = j;
        span[b * M_ + k] = best;
    }
}

// ---------------------------------------------------------------- f32 -> bf16, 5 fused segments
__global__ void f2b5_kernel(const float* __restrict__ s0, const float* __restrict__ s1,
                            const float* __restrict__ s2, const float* __restrict__ s3,
                            const float* __restrict__ s4,
                            unsigned short* __restrict__ dst,
                            int c0, int c1, int c2, int c3, int c4) {
    int i = blockIdx.x * 256 + threadIdx.x;
    if (i >= c4) return;
    float v;
    if      (i < c0) v = s0[i];
    else if (i < c1) v = s1[i - c0];
    else if (i < c2) v = s2[i - c1];
    else if (i < c3) v = s3[i - c2];
    else             v = s4[i - c3];
    dst[i] = f2b_rne(v);
}

// ---------------------------------------------------------------- build x0 (f32 + bf16 shadow), PE inline
__global__ void build_x(const float* __restrict__ emb,
                        const int* __restrict__ pos2,
                        const float* __restrict__ fbase,
                        const int* __restrict__ span,
                        float* __restrict__ x,
                        unsigned short* __restrict__ xb) {
    long long idx = (long long)blockIdx.x * blockDim.x + threadIdx.x;
    if (idx >= (long long)T_ * E_) return;
    int e = (int)(idx % E_);
    int t = (int)(idx / E_);
    int s = t % S_;
    int b = t / S_;
    float val;
    if (s == 0) {
        val = emb[E_ + e];
    } else {
        int k = s - 1;
        int sid = span[b * M_ + k];
        if (sid >= 0) {
            int p = pos2[b * M_ + sid];
            float ex = (float)((e >> 1) << 1) * (1.0f / 512.0f);
            float ang = (float)sid * exp2f(-ex * 13.287712379549449f);  // log2(10000)
            float pe = (e & 1) ? cosf(ang) : sinf(ang);
            val = emb[(size_t)p * E_ + e] + pe;
        } else {
            val = fbase[((size_t)b * M_ + k) * E_ + e];
        }
    }
    x[idx] = val;
    xb[idx] = f2b_rne(val);
}

// ---------------------------------------------------------------- bf16 MFMA GEMM (NT), global_load_lds pipelined
// A [TP_,K] bf16, W [O,K] bf16; C = act(A·W^T + bias), bf16 out.
// Block 128x128, 4 waves, wave tile 64x64 (4x4 mfma 16x16x32), BK=32.
// Direct-to-LDS staging (width 16), double-buffered, ONE barrier per K-step,
// explicit vmcnt(0) fence before the barrier (round-3 race fix).
template <int ACT, int KT>  // ACT: 0 none 1 relu 2 tanh
__global__ __launch_bounds__(256, 4) void gemm_bf16(const unsigned short* __restrict__ A,
                                                    const unsigned short* __restrict__ W,
                                                    const float* __restrict__ bias,
                                                    unsigned short* __restrict__ Cb,
                                                    int T, int O) {
    constexpr int K = KT;
    constexpr int NSTEP = K / 32;
    __shared__ __align__(16) unsigned short sA[2][128 * 32];
    __shared__ __align__(16) unsigned short sB[2][128 * 32];
    int tid = threadIdx.x;
    int lane = tid & 63, wv = tid >> 6;
    int wr = (wv >> 1) * 64, wc = (wv & 1) * 64;

    // ---- panel swizzle: 8 m-tiles per panel, n fastest within panel
    int gn = O / 128;
    int per_panel = 8 * gn;
    int id = blockIdx.x;
    int p = id / per_panel;
    int r = id - p * per_panel;
    int mrem = GMT_ - p * 8; if (mrem > 8) mrem = 8;
    int mt = p * 8 + r % mrem;
    int nt = r / mrem;
    int t0 = mt * 128, o0 = nt * 128;

    floatx4 acc[4][4] = {};

    // staging: wave wv owns rows [wv*32, wv*32+32); lane -> (row = lane>>2, chunk=(lane&3)*8)
    const unsigned short* Ag = A + (size_t)(t0 + wv * 32 + (lane >> 2)) * K + (lane & 3) * 8;
    const unsigned short* Bg = W + (size_t)(o0 + wv * 32 + (lane >> 2)) * K + (lane & 3) * 8;
    const size_t row16 = (size_t)16 * K;
    // LDS layout: row-major [128][32] shorts; wave region = wv*1024 shorts;
    // gload writes lane*16B -> (row local = lane>>2)*32 + (lane&3)*8  (matches row-major)
    unsigned short* dA0 = &sA[0][wv * 1024];
    unsigned short* dB0 = &sB[0][wv * 1024];

    int fr = lane & 15;
    int fk = (lane >> 4) * 8;

    // prologue: tile 0 -> buffer 0
    gload16(Ag, dA0);
    gload16(Ag + row16, dA0 + 512);
    gload16(Bg, dB0);
    gload16(Bg + row16, dB0 + 512);
    wait_vm0();
    __syncthreads();

#pragma unroll 2
    for (int s = 0; s < NSTEP; ++s) {
        const int cur = s & 1;
        if (s + 1 < NSTEP) {
            const int k = (s + 1) * 32;
            unsigned short* dA = &sA[cur ^ 1][wv * 1024];
            unsigned short* dB = &sB[cur ^ 1][wv * 1024];
            gload16(Ag + k, dA);
            gload16(Ag + row16 + k, dA + 512);
            gload16(Bg + k, dB);
            gload16(Bg + row16 + k, dB + 512);
        }

        short8 af[4], bfr[4];
#pragma unroll
        for (int i = 0; i < 4; ++i)
            af[i] = *(const short8*)&sA[cur][(wr + i * 16 + fr) * 32 + fk];
#pragma unroll
        for (int j = 0; j < 4; ++j)
            bfr[j] = *(const short8*)&sB[cur][(wc + j * 16 + fr) * 32 + fk];
#pragma unroll
        for (int i = 0; i < 4; ++i)
#pragma unroll
            for (int j = 0; j < 4; ++j)
                acc[i][j] = __builtin_amdgcn_mfma_f32_16x16x32_bf16(af[i], bfr[j], acc[i][j], 0, 0, 0);

        wait_vm0();          // prefetch to buf^1 landed (this wave's loads)
        __syncthreads();     // all waves' loads landed; cur fully consumed
    }

    int cr = (lane >> 4) * 4;
    int cc = lane & 15;
#pragma unroll
    for (int i = 0; i < 4; ++i) {
#pragma unroll
        for (int j = 0; j < 4; ++j) {
            int gn_ = o0 + wc + j * 16 + cc;
            float bv = bias ? bias[gn_] : 0.f;
#pragma unroll
            for (int rr = 0; rr < 4; ++rr) {
                int gm_ = t0 + wr + i * 16 + cr + rr;
                if (gm_ >= T) continue;
                float v = acc[i][j][rr] + bv;
                if (ACT == 1) v = fmaxf(v, 0.f);
                if (ACT == 2) v = tanhf(v);
                Cb[(size_t)gm_ * O + gn_] = f2b_rne(v);
            }
        }
    }
}

// ---------------------------------------------------------------- attention over the B axis (bf16 in/out)
__global__ __launch_bounds__(256) void attn_kernel(const unsigned short* __restrict__ qkv,
                                                   unsigned short* __restrict__ o) {
    __shared__ float q[32][65], kk[32][65], vv[32][65];
    __shared__ float sc[32][33];
    int s = blockIdx.x, h = blockIdx.y;
    int tid = threadIdx.x;

    for (int u = tid; u < B_ * DH_; u += 256) {
        int b = u >> 6, d = u & 63;
        size_t base = ((size_t)b * S_ + s) * 1536 + h * DH_ + d;
        q[b][d]  = bf2f(qkv[base]) * 0.125f;
        kk[b][d] = bf2f(qkv[base + 512]);
        vv[b][d] = bf2f(qkv[base + 1024]);
    }
    __syncthreads();

    for (int u = tid; u < 1024; u += 256) {
        int l = u >> 5, m = u & 31;
        float acc = 0.f;
#pragma unroll 8
        for (int d = 0; d < 64; ++d) acc += q[l][d] * kk[m][d];
        sc[l][m] = acc;
    }
    __syncthreads();

    if (tid < 32) {
        float mx = -1e30f;
        for (int m = 0; m < 32; ++m) mx = fmaxf(mx, sc[tid][m]);
        float sum = 0.f;
        for (int m = 0; m < 32; ++m) { float e = expf(sc[tid][m] - mx); sc[tid][m] = e; sum += e; }
        float inv = 1.f / sum;
        for (int m = 0; m < 32; ++m) sc[tid][m] *= inv;
    }
    __syncthreads();

    for (int u = tid; u < B_ * DH_; u += 256) {
        int l = u >> 6, d = u & 63;
        float acc = 0.f;
#pragma unroll 8
        for (int m = 0; m < 32; ++m) acc += sc[l][m] * vv[m][d];
        o[((size_t)l * S_ + s) * E_ + h * DH_ + d] = f2b_rne(acc);
    }
}

// ---------------------------------------------------------------- x = LN(x + h); h in bf16; writes f32 + bf16 shadow
__global__ __launch_bounds__(256) void add_ln(float* __restrict__ x,
                                              unsigned short* __restrict__ xb,
                                              const unsigned short* __restrict__ h,
                                              const float* __restrict__ w,
                                              const float* __restrict__ b) {
    int t = blockIdx.x;
    float* xr = x + (size_t)t * E_;
    const unsigned short* hr = h + (size_t)t * E_;
    int i0 = threadIdx.x * 2;
    float2 xv = *(const float2*)&xr[i0];
    ushort2 hv = *(const ushort2*)&hr[i0];
    float v0 = xv.x + bf2f(hv.x), v1 = xv.y + bf2f(hv.y);

    __shared__ float red[4];
    float sum = v0 + v1;
    for (int off = 32; off; off >>= 1) sum += __shfl_down(sum, off);
    if ((threadIdx.x & 63) == 0) red[threadIdx.x >> 6] = sum;
    __syncthreads();
    float mu = (red[0] + red[1] + red[2] + red[3]) * (1.0f / E_);
    __syncthreads();

    float d0 = v0 - mu, d1 = v1 - mu;
    float qs = d0 * d0 + d1 * d1;
    for (int off = 32; off; off >>= 1) qs += __shfl_down(qs, off);
    if ((threadIdx.x & 63) == 0) red[threadIdx.x >> 6] = qs;
    __syncthreads();
    float var = (red[0] + red[1] + red[2] + red[3]) * (1.0f / E_);
    float rstd = rsqrtf(var + 1e-5f);

    float o0 = d0 * rstd * w[i0]     + b[i0];
    float o1 = d1 * rstd * w[i0 + 1] + b[i0 + 1];
    *(float2*)&xr[i0] = make_float2(o0, o1);
    xb[(size_t)t * E_ + i0]     = f2b_rne(o0);
    xb[(size_t)t * E_ + i0 + 1] = f2b_rne(o1);
}

// ---------------------------------------------------------------- discriminator + sigmoid (pf in bf16)
__global__ __launch_bounds__(256) void disc_kernel(const float* __restrict__ bert,
                                                   const unsigned short* __restrict__ pf,
                                                   const float* __restrict__ wd,
                                                   const float* __restrict__ bd,
                                                   float* __restrict__ out) {
    int t = blockIdx.x;
    float s = 0.f;
    for (int f = threadIdx.x; f < F_; f += 256) {
        s += bert[(size_t)t * F_ + f] * wd[f];
        s += bf2f(pf[(size_t)t * F_ + f]) * wd[F_ + f];
    }
    for (int off = 32; off; off >>= 1) s += __shfl_down(s, off);
    __shared__ float red[4];
    if ((threadIdx.x & 63) == 0) red[threadIdx.x >> 6] = s;
    __syncthreads();
    if (threadIdx.x == 0) {
        float z = red[0] + red[1] + red[2] + red[3] + bd[0];
        out[t] = 1.f / (1.f + expf(-z));
    }
}

// ---------------------------------------------------------------- launch
extern "C" void kernel_launch(void* const* d_in, const int* in_sizes, int n_in,
                              void* d_out, int out_size, void* d_ws, size_t ws_size,
                              hipStream_t stream) {
    const int*   pos1 = (const int*)d_in[0];
    const int*   pos2 = (const int*)d_in[1];
    const float* bert = (const float*)d_in[2];
    const float* fb   = (const float*)d_in[3];
    const float* emb  = (const float*)d_in[4];
    const float* wi   = (const float*)d_in[5];
    const float* bi   = (const float*)d_in[6];
    const float* wo   = (const float*)d_in[7];
    const float* bo   = (const float*)d_in[8];
    const float* ln1w = (const float*)d_in[9];
    const float* ln1b = (const float*)d_in[10];
    const float* ln2w = (const float*)d_in[11];
    const float* ln2b = (const float*)d_in[12];
    const float* w1   = (const float*)d_in[13];
    const float* b1   = (const float*)d_in[14];
    const float* w2   = (const float*)d_in[15];
    const float* b2   = (const float*)d_in[16];
    const float* wm   = (const float*)d_in[17];
    const float* wd   = (const float*)d_in[18];
    const float* bd   = (const float*)d_in[19];
    float* out = (float*)d_out;

    // workspace layout
    float* ws   = (float*)d_ws;
    int*   span = (int*)ws;                                   // 16384 i
    float* x    = ws + 16384;                                 // T_*512 f
    unsigned short* xb  = (unsigned short*)(x + (size_t)T_ * 512);   // TP_*512 bf16
    unsigned short* atb = xb + (size_t)TP_ * 512;                    // TP_*512 bf16
    unsigned short* hb  = atb + (size_t)TP_ * 512;                   // T_*512 bf16
    unsigned short* U   = hb + (size_t)T_ * 512;              // union: qkv | h1 | pf
    unsigned short* qkvb = U;
    unsigned short* h1b  = U;
    unsigned short* pfb  = U;
    unsigned short* wib  = U + (size_t)TP_ * 2048;            // weights bf16, contiguous
    const int NWI = 2 * 1536 * 512;
    const int NWO = 2 * 512 * 512;
    const int NW1 = 2 * 2048 * 512;
    const int NW2 = 2 * 512 * 2048;
    const int NWM = 768 * 512;
    unsigned short* wob = wib + NWI;
    unsigned short* w1b = wob + NWO;
    unsigned short* w2b = w1b + NW1;
    unsigned short* wmb = w2b + NW2;

    span_kernel<<<B_, 256, 0, stream>>>(pos1, span);
    {
        int c0 = NWI, c1 = c0 + NWO, c2 = c1 + NW1, c3 = c2 + NW2, c4 = c3 + NWM;
        f2b5_kernel<<<(c4 + 255) / 256, 256, 0, stream>>>(wi, wo, w1, w2, wm, wib,
                                                          c0, c1, c2, c3, c4);
    }
    build_x<<<(int)(((long long)T_ * 512 + 255) / 256), 256, 0, stream>>>(emb, pos2, fb, span, x, xb);

    for (int l = 0; l < 2; ++l) {
        gemm_bf16<0, 512><<<GMT_ * (1536 / 128), 256, 0, stream>>>(
            xb, wib + (size_t)l * 1536 * 512, bi + l * 1536, qkvb, T_, 1536);
        attn_kernel<<<dim3(S_, NH_), 256, 0, stream>>>(qkvb, atb);
        gemm_bf16<0, 512><<<GMT_ * (512 / 128), 256, 0, stream>>>(
            atb, wob + (size_t)l * 512 * 512, bo + l * 512, hb, T_, 512);
        add_ln<<<T_, 256, 0, stream>>>(x, xb, hb, ln1w + l * 512, ln1b + l * 512);
        gemm_bf16<1, 512><<<GMT_ * (2048 / 128), 256, 0, stream>>>(
            xb, w1b + (size_t)l * 2048 * 512, b1 + l * 2048, h1b, T_, 2048);
        gemm_bf16<0, 2048><<<GMT_ * (512 / 128), 256, 0, stream>>>(
            h1b, w2b + (size_t)l * 512 * 2048, b2 + l * 512, hb, T_, 512);
        add_ln<<<T_, 256, 0, stream>>>(x, xb, hb, ln2w + l * 512, ln2b + l * 512);
    }
    gemm_bf16<2, 512><<<GMT_ * (768 / 128), 256, 0, stream>>>(
        xb, wmb, nullptr, pfb, T_, 768);
    disc_kernel<<<T_, 256, 0, stream>>>(bert, pfb, wd, bd, out);
}

// Round 8
// 777.116 us; speedup vs baseline: 6.2273x; 1.1393x over previous
//
#include <hip/hip_runtime.h>
#include <hip/hip_bf16.h>

#define B_   32
#define M_   512
#define E_   512
#define S_   513            // M+1
#define T_   (B_ * S_)      // 16416 tokens
#define TP_  16512          // 129*128 padded
#define NH_  8
#define DH_  64
#define F_   768
#define DFF_ 2048

#define GMT_ 129            // m tiles

typedef short short8 __attribute__((ext_vector_type(8)));
typedef float floatx4 __attribute__((ext_vector_type(4)));

__device__ __forceinline__ float bf2f(unsigned short u) {
    return __uint_as_float(((unsigned int)u) << 16);
}
__device__ __forceinline__ unsigned short f2b_rne(float f) {
    unsigned int u = __float_as_uint(f);
    unsigned int r = u + 0x7FFF + ((u >> 16) & 1);
    return (unsigned short)(r >> 16);
}
__device__ __forceinline__ void gload16(const void* g, void* l) {
    __builtin_amdgcn_global_load_lds(
        (const __attribute__((address_space(1))) void*)g,
        (__attribute__((address_space(3))) void*)l, 16, 0, 0);
}
// wait vmcnt(0) only (expcnt=7, lgkmcnt=15 -> no wait): gfx9 encoding 0x0F70
__device__ __forceinline__ void wait_vm0() { __builtin_amdgcn_s_waitcnt(0x0F70); }

// ---------------------------------------------------------------- span ids
__global__ void span_kernel(const int* __restrict__ pos1, int* __restrict__ span) {
    int b = blockIdx.x;
    __shared__ int st[M_], en[M_];
    __shared__ int nv;
    int tid = threadIdx.x;
    for (int j = tid; j < M_; j += 256) {
        st[j] = pos1[(b * M_ + j) * 2];
        en[j] = pos1[(b * M_ + j) * 2 + 1];
    }
    __syncthreads();
    if (tid == 0) {
        int n = M_;
        for (int j = 0; j < M_; ++j) if (en[j] == 0) { n = j; break; }
        nv = n;
    }
    __syncthreads();
    int n = nv;
    for (int k = tid; k < M_; k += 256) {
        int best = -1;
        for (int j = 0; j < n; ++j)
            if (st[j] <= k && k < en[j]) best = j;
        span[b * M_ + k] = best;
    }
}

// ---------------------------------------------------------------- f32 -> bf16, 5 fused segments
__global__ void f2b5_kernel(const float* __restrict__ s0, const float* __restrict__ s1,
                            const float* __restrict__ s2, const float* __restrict__ s3,
                            const float* __restrict__ s4,
                            unsigned short* __restrict__ dst,
                            int c0, int c1, int c2, int c3, int c4) {
    int i = blockIdx.x * 256 + threadIdx.x;
    if (i >= c4) return;
    float v;
    if      (i < c0) v = s0[i];
    else if (i < c1) v = s1[i - c0];
    else if (i < c2) v = s2[i - c1];
    else if (i < c3) v = s3[i - c2];
    else             v = s4[i - c3];
    dst[i] = f2b_rne(v);
}

// ---------------------------------------------------------------- build x0 (f32 + bf16 shadow), PE inline
__global__ void build_x(const float* __restrict__ emb,
                        const int* __restrict__ pos2,
                        const float* __restrict__ fbase,
                        const int* __restrict__ span,
                        float* __restrict__ x,
                        unsigned short* __restrict__ xb) {
    long long idx = (long long)blockIdx.x * blockDim.x + threadIdx.x;
    if (idx >= (long long)T_ * E_) return;
    int e = (int)(idx % E_);
    int t = (int)(idx / E_);
    int s = t % S_;
    int b = t / S_;
    float val;
    if (s == 0) {
        val = emb[E_ + e];
    } else {
        int k = s - 1;
        int sid = span[b * M_ + k];
        if (sid >= 0) {
            int p = pos2[b * M_ + sid];
            float ex = (float)((e >> 1) << 1) * (1.0f / 512.0f);
            float ang = (float)sid * exp2f(-ex * 13.287712379549449f);  // log2(10000)
            float pe = (e & 1) ? cosf(ang) : sinf(ang);
            val = emb[(size_t)p * E_ + e] + pe;
        } else {
            val = fbase[((size_t)b * M_ + k) * E_ + e];
        }
    }
    x[idx] = val;
    xb[idx] = f2b_rne(val);
}

// ---------------------------------------------------------------- bf16 MFMA GEMM (NT), global_load_lds pipelined
template <int ACT, int KT>  // ACT: 0 none 1 relu 2 tanh
__global__ __launch_bounds__(256, 4) void gemm_bf16(const unsigned short* __restrict__ A,
                                                    const unsigned short* __restrict__ W,
                                                    const float* __restrict__ bias,
                                                    unsigned short* __restrict__ Cb,
                                                    int T, int O) {
    constexpr int K = KT;
    constexpr int NSTEP = K / 32;
    __shared__ __align__(16) unsigned short sA[2][128 * 32];
    __shared__ __align__(16) unsigned short sB[2][128 * 32];
    int tid = threadIdx.x;
    int lane = tid & 63, wv = tid >> 6;
    int wr = (wv >> 1) * 64, wc = (wv & 1) * 64;

    // ---- panel swizzle: 8 m-tiles per panel, n fastest within panel
    int gn = O / 128;
    int per_panel = 8 * gn;
    int id = blockIdx.x;
    int p = id / per_panel;
    int r = id - p * per_panel;
    int mrem = GMT_ - p * 8; if (mrem > 8) mrem = 8;
    int mt = p * 8 + r % mrem;
    int nt = r / mrem;
    int t0 = mt * 128, o0 = nt * 128;

    floatx4 acc[4][4] = {};

    const unsigned short* Ag = A + (size_t)(t0 + wv * 32 + (lane >> 2)) * K + (lane & 3) * 8;
    const unsigned short* Bg = W + (size_t)(o0 + wv * 32 + (lane >> 2)) * K + (lane & 3) * 8;
    const size_t row16 = (size_t)16 * K;
    unsigned short* dA0 = &sA[0][wv * 1024];
    unsigned short* dB0 = &sB[0][wv * 1024];

    int fr = lane & 15;
    int fk = (lane >> 4) * 8;

    gload16(Ag, dA0);
    gload16(Ag + row16, dA0 + 512);
    gload16(Bg, dB0);
    gload16(Bg + row16, dB0 + 512);
    wait_vm0();
    __syncthreads();

#pragma unroll 2
    for (int s = 0; s < NSTEP; ++s) {
        const int cur = s & 1;
        if (s + 1 < NSTEP) {
            const int k = (s + 1) * 32;
            unsigned short* dA = &sA[cur ^ 1][wv * 1024];
            unsigned short* dB = &sB[cur ^ 1][wv * 1024];
            gload16(Ag + k, dA);
            gload16(Ag + row16 + k, dA + 512);
            gload16(Bg + k, dB);
            gload16(Bg + row16 + k, dB + 512);
        }

        short8 af[4], bfr[4];
#pragma unroll
        for (int i = 0; i < 4; ++i)
            af[i] = *(const short8*)&sA[cur][(wr + i * 16 + fr) * 32 + fk];
#pragma unroll
        for (int j = 0; j < 4; ++j)
            bfr[j] = *(const short8*)&sB[cur][(wc + j * 16 + fr) * 32 + fk];
#pragma unroll
        for (int i = 0; i < 4; ++i)
#pragma unroll
            for (int j = 0; j < 4; ++j)
                acc[i][j] = __builtin_amdgcn_mfma_f32_16x16x32_bf16(af[i], bfr[j], acc[i][j], 0, 0, 0);

        wait_vm0();
        __syncthreads();
    }

    int cr = (lane >> 4) * 4;
    int cc = lane & 15;
#pragma unroll
    for (int i = 0; i < 4; ++i) {
#pragma unroll
        for (int j = 0; j < 4; ++j) {
            int gn_ = o0 + wc + j * 16 + cc;
            float bv = bias ? bias[gn_] : 0.f;
#pragma unroll
            for (int rr = 0; rr < 4; ++rr) {
                int gm_ = t0 + wr + i * 16 + cr + rr;
                if (gm_ >= T) continue;
                float v = acc[i][j][rr] + bv;
                if (ACT == 1) v = fmaxf(v, 0.f);
                if (ACT == 2) v = tanhf(v);
                Cb[(size_t)gm_ * O + gn_] = f2b_rne(v);
            }
        }
    }
}

// ---------------------------------------------------------------- MFMA attention: one wave per (s,h)
// scores S[l][m] = (q_l . k_m) * 0.125 over d=64; softmax over m; O = P.V
// Q/K A/B-frags loaded directly from global; V transposed into LDS; P via LDS.
__global__ __launch_bounds__(64) void attn_mfma(const unsigned short* __restrict__ qkv,
                                                unsigned short* __restrict__ o) {
    __shared__ __align__(16) unsigned short vt[64 * 40];   // V^T [d][m], stride 40
    __shared__ __align__(16) unsigned short ps[32 * 40];   // P [l][m], stride 40
    int s = blockIdx.x, h = blockIdx.y;
    int lane = threadIdx.x;
    int hd = h * 64;
    int fr = lane & 15, fq = lane >> 4;

    // ---- stage V transposed: lane loads v[m = lane>>1][(lane&1)*32 .. +32]
    {
        int m = lane >> 1;
        int d0 = (lane & 1) * 32;
        const unsigned short* vrow = qkv + ((size_t)m * S_ + s) * 1536 + 1024 + hd + d0;
        short8 v0 = *(const short8*)(vrow);
        short8 v1 = *(const short8*)(vrow + 8);
        short8 v2 = *(const short8*)(vrow + 16);
        short8 v3 = *(const short8*)(vrow + 24);
#pragma unroll
        for (int j = 0; j < 8; ++j) {
            vt[(d0 + j) * 40 + m]      = (unsigned short)v0[j];
            vt[(d0 + 8 + j) * 40 + m]  = (unsigned short)v1[j];
            vt[(d0 + 16 + j) * 40 + m] = (unsigned short)v2[j];
            vt[(d0 + 24 + j) * 40 + m] = (unsigned short)v3[j];
        }
    }

    // ---- QK^T: 2x2 tiles, K=64 in 2 steps
    floatx4 c[2][2] = {};
#pragma unroll
    for (int ks = 0; ks < 2; ++ks) {
        short8 aq[2], bk[2];
#pragma unroll
        for (int lt = 0; lt < 2; ++lt) {
            int l = lt * 16 + fr;
            aq[lt] = *(const short8*)(qkv + ((size_t)l * S_ + s) * 1536 + hd + ks * 32 + fq * 8);
        }
#pragma unroll
        for (int mt = 0; mt < 2; ++mt) {
            int m = mt * 16 + fr;
            bk[mt] = *(const short8*)(qkv + ((size_t)m * S_ + s) * 1536 + 512 + hd + ks * 32 + fq * 8);
        }
#pragma unroll
        for (int lt = 0; lt < 2; ++lt)
#pragma unroll
            for (int mt = 0; mt < 2; ++mt)
                c[lt][mt] = __builtin_amdgcn_mfma_f32_16x16x32_bf16(aq[lt], bk[mt], c[lt][mt], 0, 0, 0);
    }

    // ---- softmax over m (cols across lane&15 and the 2 m-tiles), write P to LDS
#pragma unroll
    for (int lt = 0; lt < 2; ++lt) {
#pragma unroll
        for (int r = 0; r < 4; ++r) {
            float a = c[lt][0][r] * 0.125f;
            float b = c[lt][1][r] * 0.125f;
            float mx = fmaxf(a, b);
#pragma unroll
            for (int off = 1; off < 16; off <<= 1) mx = fmaxf(mx, __shfl_xor(mx, off));
            float ea = expf(a - mx), eb = expf(b - mx);
            float sm = ea + eb;
#pragma unroll
            for (int off = 1; off < 16; off <<= 1) sm += __shfl_xor(sm, off);
            float inv = 1.f / sm;
            int l = lt * 16 + fq * 4 + r;
            ps[l * 40 + fr]      = f2b_rne(ea * inv);
            ps[l * 40 + 16 + fr] = f2b_rne(eb * inv);
        }
    }
    __syncthreads();

    // ---- PV: A-frags from ps, B-frags from vt, K=32 (one mfma per tile)
    short8 pa[2], vb[4];
#pragma unroll
    for (int lt = 0; lt < 2; ++lt)
        pa[lt] = *(const short8*)&ps[(lt * 16 + fr) * 40 + fq * 8];
#pragma unroll
    for (int dt = 0; dt < 4; ++dt)
        vb[dt] = *(const short8*)&vt[(dt * 16 + fr) * 40 + fq * 8];

    floatx4 oa[2][4] = {};
#pragma unroll
    for (int lt = 0; lt < 2; ++lt)
#pragma unroll
        for (int dt = 0; dt < 4; ++dt)
            oa[lt][dt] = __builtin_amdgcn_mfma_f32_16x16x32_bf16(pa[lt], vb[dt], oa[lt][dt], 0, 0, 0);

#pragma unroll
    for (int lt = 0; lt < 2; ++lt)
#pragma unroll
        for (int dt = 0; dt < 4; ++dt)
#pragma unroll
            for (int r = 0; r < 4; ++r) {
                int l = lt * 16 + fq * 4 + r;
                o[((size_t)l * S_ + s) * E_ + hd + dt * 16 + fr] = f2b_rne(oa[lt][dt][r]);
            }
}

// ---------------------------------------------------------------- x = LN(x + h); h in bf16; writes f32 + bf16 shadow
__global__ __launch_bounds__(256) void add_ln(float* __restrict__ x,
                                              unsigned short* __restrict__ xb,
                                              const unsigned short* __restrict__ h,
                                              const float* __restrict__ w,
                                              const float* __restrict__ b) {
    int t = blockIdx.x;
    float* xr = x + (size_t)t * E_;
    const unsigned short* hr = h + (size_t)t * E_;
    int i0 = threadIdx.x * 2;
    float2 xv = *(const float2*)&xr[i0];
    ushort2 hv = *(const ushort2*)&hr[i0];
    float v0 = xv.x + bf2f(hv.x), v1 = xv.y + bf2f(hv.y);

    __shared__ float red[4];
    float sum = v0 + v1;
    for (int off = 32; off; off >>= 1) sum += __shfl_down(sum, off);
    if ((threadIdx.x & 63) == 0) red[threadIdx.x >> 6] = sum;
    __syncthreads();
    float mu = (red[0] + red[1] + red[2] + red[3]) * (1.0f / E_);
    __syncthreads();

    float d0 = v0 - mu, d1 = v1 - mu;
    float qs = d0 * d0 + d1 * d1;
    for (int off = 32; off; off >>= 1) qs += __shfl_down(qs, off);
    if ((threadIdx.x & 63) == 0) red[threadIdx.x >> 6] = qs;
    __syncthreads();
    float var = (red[0] + red[1] + red[2] + red[3]) * (1.0f / E_);
    float rstd = rsqrtf(var + 1e-5f);

    float o0 = d0 * rstd * w[i0]     + b[i0];
    float o1 = d1 * rstd * w[i0 + 1] + b[i0 + 1];
    *(float2*)&xr[i0] = make_float2(o0, o1);
    xb[(size_t)t * E_ + i0]     = f2b_rne(o0);
    xb[(size_t)t * E_ + i0 + 1] = f2b_rne(o1);
}

// ---------------------------------------------------------------- discriminator + sigmoid (pf in bf16)
__global__ __launch_bounds__(256) void disc_kernel(const float* __restrict__ bert,
                                                   const unsigned short* __restrict__ pf,
                                                   const float* __restrict__ wd,
                                                   const float* __restrict__ bd,
                                                   float* __restrict__ out) {
    int t = blockIdx.x;
    float s = 0.f;
    for (int f = threadIdx.x; f < F_; f += 256) {
        s += bert[(size_t)t * F_ + f] * wd[f];
        s += bf2f(pf[(size_t)t * F_ + f]) * wd[F_ + f];
    }
    for (int off = 32; off; off >>= 1) s += __shfl_down(s, off);
    __shared__ float red[4];
    if ((threadIdx.x & 63) == 0) red[threadIdx.x >> 6] = s;
    __syncthreads();
    if (threadIdx.x == 0) {
        float z = red[0] + red[1] + red[2] + red[3] + bd[0];
        out[t] = 1.f / (1.f + expf(-z));
    }
}

// ---------------------------------------------------------------- launch
extern "C" void kernel_launch(void* const* d_in, const int* in_sizes, int n_in,
                              void* d_out, int out_size, void* d_ws, size_t ws_size,
                              hipStream_t stream) {
    const int*   pos1 = (const int*)d_in[0];
    const int*   pos2 = (const int*)d_in[1];
    const float* bert = (const float*)d_in[2];
    const float* fb   = (const float*)d_in[3];
    const float* emb  = (const float*)d_in[4];
    const float* wi   = (const float*)d_in[5];
    const float* bi   = (const float*)d_in[6];
    const float* wo   = (const float*)d_in[7];
    const float* bo   = (const float*)d_in[8];
    const float* ln1w = (const float*)d_in[9];
    const float* ln1b = (const float*)d_in[10];
    const float* ln2w = (const float*)d_in[11];
    const float* ln2b = (const float*)d_in[12];
    const float* w1   = (const float*)d_in[13];
    const float* b1   = (const float*)d_in[14];
    const float* w2   = (const float*)d_in[15];
    const float* b2   = (const float*)d_in[16];
    const float* wm   = (const float*)d_in[17];
    const float* wd   = (const float*)d_in[18];
    const float* bd   = (const float*)d_in[19];
    float* out = (float*)d_out;

    // workspace layout
    float* ws   = (float*)d_ws;
    int*   span = (int*)ws;                                   // 16384 i
    float* x    = ws + 16384;                                 // T_*512 f
    unsigned short* xb  = (unsigned short*)(x + (size_t)T_ * 512);   // TP_*512 bf16
    unsigned short* atb = xb + (size_t)TP_ * 512;                    // TP_*512 bf16
    unsigned short* hb  = atb + (size_t)TP_ * 512;                   // T_*512 bf16
    unsigned short* U   = hb + (size_t)T_ * 512;              // union: qkv | h1 | pf
    unsigned short* qkvb = U;
    unsigned short* h1b  = U;
    unsigned short* pfb  = U;
    unsigned short* wib  = U + (size_t)TP_ * 2048;            // weights bf16, contiguous
    const int NWI = 2 * 1536 * 512;
    const int NWO = 2 * 512 * 512;
    const int NW1 = 2 * 2048 * 512;
    const int NW2 = 2 * 512 * 2048;
    const int NWM = 768 * 512;
    unsigned short* wob = wib + NWI;
    unsigned short* w1b = wob + NWO;
    unsigned short* w2b = w1b + NW1;
    unsigned short* wmb = w2b + NW2;

    span_kernel<<<B_, 256, 0, stream>>>(pos1, span);
    {
        int c0 = NWI, c1 = c0 + NWO, c2 = c1 + NW1, c3 = c2 + NW2, c4 = c3 + NWM;
        f2b5_kernel<<<(c4 + 255) / 256, 256, 0, stream>>>(wi, wo, w1, w2, wm, wib,
                                                          c0, c1, c2, c3, c4);
    }
    build_x<<<(int)(((long long)T_ * 512 + 255) / 256), 256, 0, stream>>>(emb, pos2, fb, span, x, xb);

    for (int l = 0; l < 2; ++l) {
        gemm_bf16<0, 512><<<GMT_ * (1536 / 128), 256, 0, stream>>>(
            xb, wib + (size_t)l * 1536 * 512, bi + l * 1536, qkvb, T_, 1536);
        attn_mfma<<<dim3(S_, NH_), 64, 0, stream>>>(qkvb, atb);
        gemm_bf16<0, 512><<<GMT_ * (512 / 128), 256, 0, stream>>>(
            atb, wob + (size_t)l * 512 * 512, bo + l * 512, hb, T_, 512);
        add_ln<<<T_, 256, 0, stream>>>(x, xb, hb, ln1w + l * 512, ln1b + l * 512);
        gemm_bf16<1, 512><<<GMT_ * (2048 / 128), 256, 0, stream>>>(
            xb, w1b + (size_t)l * 2048 * 512, b1 + l * 2048, h1b, T_, 2048);
        gemm_bf16<0, 2048><<<GMT_ * (512 / 128), 256, 0, stream>>>(
            h1b, w2b + (size_t)l * 512 * 2048, b2 + l * 512, hb, T_, 512);
        add_ln<<<T_, 256, 0, stream>>>(x, xb, hb, ln2w + l * 512, ln2b + l * 512);
    }
    gemm_bf16<2, 512><<<GMT_ * (768 / 128), 256, 0, stream>>>(
        xb, wmb, nullptr, pfb, T_, 768);
    disc_kernel<<<T_, 256, 0, stream>>>(bert, pfb, wd, bd, out);
}